// Round 1
// baseline (2420.366 us; speedup 1.0000x reference)
//
#include <hip/hip_runtime.h>
#include <stdint.h>

#define S_ 1024
#define D_ 1024
#define H_ 16
#define DH_ 64
#define FF_ 4096
#define B_ 2
#define V_ 32000
#define CTX_ 1025
#define PAD_ 3

typedef unsigned short u16;
typedef __attribute__((ext_vector_type(8))) short bf16x8;
typedef __attribute__((ext_vector_type(4))) float f32x4;

enum { EPI_BF16 = 0, EPI_QKV = 1, EPI_FC = 2, EPI_GELU_BF16 = 3, EPI_GELU_RES = 4, EPI_BIAS_F32 = 5 };

__device__ __forceinline__ u16 f2bf(float f) {
  unsigned u = __float_as_uint(f);
  return (u16)((u + 0x7FFFu + ((u >> 16) & 1u)) >> 16);
}

__device__ __forceinline__ float gelu_f(float x) {
  float t = tanhf(0.7978845608028654f * (x + 0.044715f * x * x * x));
  return 0.5f * x * (1.0f + t);
}

__device__ __forceinline__ void glds16(const void* g, void* l) {
  __builtin_amdgcn_global_load_lds(
      (const __attribute__((address_space(1))) unsigned int*)g,
      (__attribute__((address_space(3))) unsigned int*)l,
      16, 0, 0);
}

// ---------------- embedding gather ----------------
__global__ __launch_bounds__(256) void embed_gather(const int* __restrict__ text,
                                                    const float* __restrict__ emb,
                                                    float* __restrict__ x) {
  int row = blockIdx.x;             // 0..2047  (b*1024 + s)
  int b = row >> 10, s = row & 1023;
  int id = text[b * CTX_ + s];
  float4 v = ((const float4*)(emb + (size_t)id * D_))[threadIdx.x];
  ((float4*)(x + (size_t)row * D_))[threadIdx.x] = v;
}

// ---------------- relative positional encoding (bf16) ----------------
__global__ __launch_bounds__(256) void rel_enc(u16* __restrict__ rel) {
  int i = blockIdx.x;               // 0..1023
  float pos = (float)(S_ - 1 - i);
  for (int t = threadIdx.x; t < 512; t += 256) {
    float invf = exp2f(-(float)t * (13.287712379549449f / 512.0f)); // 10000^(-t/512)
    float ang = pos * invf;
    rel[(size_t)i * D_ + t] = f2bf(sinf(ang));
    rel[(size_t)i * D_ + 512 + t] = f2bf(cosf(ang));
  }
}

// ---------------- weight convert f32 (K,N) -> bf16 (N,K), z-batched ----------------
__global__ __launch_bounds__(256) void wconv_t(const float* __restrict__ src,
                                               u16* __restrict__ dst, int K, int N) {
  src += (size_t)blockIdx.z * K * N;
  dst += (size_t)blockIdx.z * K * N;
  __shared__ float tile[32][33];
  int n0 = blockIdx.x * 32, k0 = blockIdx.y * 32;
  for (int idx = threadIdx.x; idx < 1024; idx += 256) {
    int r = idx >> 5, c = idx & 31;                 // r: k, c: n
    tile[r][c] = src[(size_t)(k0 + r) * N + n0 + c];
  }
  __syncthreads();
  for (int idx = threadIdx.x; idx < 1024; idx += 256) {
    int r = idx >> 5, c = idx & 31;                 // r: n, c: k
    dst[(size_t)(n0 + r) * K + k0 + c] = f2bf(tile[c][r]);
  }
}

// ---------------- 4-way weight convert (Wq,Wk,Wv -> qkv segments; Wfc -> fc) ----------------
__global__ __launch_bounds__(256) void wconv4_k(const float* __restrict__ sq,
                                                const float* __restrict__ sk,
                                                const float* __restrict__ sv,
                                                const float* __restrict__ sf,
                                                u16* __restrict__ dqkv,
                                                u16* __restrict__ dfc) {
  const int z = blockIdx.z;
  const float* src = (z == 0) ? sq : (z == 1) ? sk : (z == 2) ? sv : sf;
  u16* dst = (z < 3) ? dqkv + (size_t)z * 1024 * 1024 : dfc;
  __shared__ float tile[32][33];
  int n0 = blockIdx.x * 32, k0 = blockIdx.y * 32;
  for (int idx = threadIdx.x; idx < 1024; idx += 256) {
    int r = idx >> 5, c = idx & 31;
    tile[r][c] = src[(size_t)(k0 + r) * 1024 + n0 + c];
  }
  __syncthreads();
  for (int idx = threadIdx.x; idx < 1024; idx += 256) {
    int r = idx >> 5, c = idx & 31;
    dst[(size_t)(n0 + r) * 1024 + k0 + c] = f2bf(tile[c][r]);
  }
}

// ---------------- layernorm (block per row) ----------------
__global__ __launch_bounds__(256) void layernorm_k(const float* __restrict__ x,
                                                   const float* __restrict__ g,
                                                   const float* __restrict__ bb,
                                                   float* __restrict__ outf,
                                                   u16* __restrict__ outb) {
  int row = blockIdx.x, tid = threadIdx.x;
  const float* xr = x + (size_t)row * D_;
  float4 v = ((const float4*)xr)[tid];
  float s = v.x + v.y + v.z + v.w;
  float s2 = v.x * v.x + v.y * v.y + v.z * v.z + v.w * v.w;
  __shared__ float red[8];
#pragma unroll
  for (int off = 32; off > 0; off >>= 1) { s += __shfl_xor(s, off); s2 += __shfl_xor(s2, off); }
  if ((tid & 63) == 0) { red[tid >> 6] = s; red[4 + (tid >> 6)] = s2; }
  __syncthreads();
  s = red[0] + red[1] + red[2] + red[3];
  s2 = red[4] + red[5] + red[6] + red[7];
  float mean = s * (1.0f / D_);
  float var = s2 * (1.0f / D_) - mean * mean;
  float rstd = rsqrtf(var + 1e-5f);
  float4 gv = ((const float4*)g)[tid];
  float4 bv = ((const float4*)bb)[tid];
  float y0 = (v.x - mean) * rstd * gv.x + bv.x;
  float y1 = (v.y - mean) * rstd * gv.y + bv.y;
  float y2 = (v.z - mean) * rstd * gv.z + bv.z;
  float y3 = (v.w - mean) * rstd * gv.w + bv.w;
  if (outf) ((float4*)(outf + (size_t)row * D_))[tid] = make_float4(y0, y1, y2, y3);
  ((ushort4*)(outb + (size_t)row * D_))[tid] = make_ushort4(f2bf(y0), f2bf(y1), f2bf(y2), f2bf(y3));
}

// ---------------- shared GEMM epilogue ----------------
__device__ __forceinline__ void epi_one(int mode, float v, int row, int col, int ldc,
                                        void* C0p, void* C1p, void* C2p, void* C3p,
                                        const float* bias0, const float* bias1,
                                        const float* res0) {
  if (mode == EPI_QKV) {
    // cols [0,1024): Q -> qu=q+u, qv=q+v ; [1024,2048): K ; [2048,3072): V
    int seg = col >> 10, c = col & 1023;
    size_t idx = (size_t)row * 1024 + c;
    if (seg == 0) {
      ((u16*)C0p)[idx] = f2bf(v + bias0[c]);
      ((u16*)C1p)[idx] = f2bf(v + bias1[c]);
    } else if (seg == 1) {
      ((u16*)C2p)[idx] = f2bf(v);
    } else {
      ((u16*)C3p)[idx] = f2bf(v);
    }
    return;
  }
  size_t idx = (size_t)row * ldc + col;
  float b0 = bias0 ? bias0[col] : 0.0f;
  if (mode == EPI_BF16) {
    ((u16*)C0p)[idx] = f2bf(v);
  } else if (mode == EPI_FC) {
    float* C0 = (float*)C0p;
    C0[idx] = C0[idx] + v + b0 + res0[idx];
  } else if (mode == EPI_GELU_BF16) {
    ((u16*)C0p)[idx] = f2bf(gelu_f(v + b0));
  } else if (mode == EPI_GELU_RES) {
    float* C0 = (float*)C0p;
    C0[idx] = C0[idx] + gelu_f(v + b0);
  } else { // EPI_BIAS_F32
    ((float*)C0p)[idx] = v + b0;
  }
}

// ---------------- main GEMM: C(M,N) = A(M,K) @ Bt(N,K)^T ----------------
// 128x128 tile, BK=32, 4 waves (2x2), each wave 64x64 via 4x4 mfma_f32_16x16x32_bf16.
__global__ __launch_bounds__(256) void gemm_bt(const u16* __restrict__ A,
                                               const u16* __restrict__ Bt,
                                               int M, int N, int K,
                                               void* __restrict__ C0p, void* __restrict__ C1p,
                                               void* __restrict__ C2p, void* __restrict__ C3p,
                                               const float* __restrict__ bias0,
                                               const float* __restrict__ bias1,
                                               const float* __restrict__ res0,
                                               int ldc, int mode) {
  __shared__ u16 lA[128 * 32];
  __shared__ u16 lB[128 * 32];
  const int tid = threadIdx.x;
  const int wave = tid >> 6, lane = tid & 63;
  const int i0 = blockIdx.y * 128, j0 = blockIdx.x * 128;
  const int wm = wave & 1, wn = wave >> 1;
  const int m_lane = lane & 15, quad = lane >> 4;

  f32x4 acc[4][4] = {};

  const u16* Ab = A + (size_t)i0 * K;
  const u16* Bb = Bt + (size_t)j0 * K;
  const int r0 = wave * 32 + (lane >> 2);
  const int cb = (lane & 3) * 8;

  for (int k0 = 0; k0 < K; k0 += 32) {
    glds16(Ab + (size_t)r0 * K + k0 + cb, lA + wave * 1024);
    glds16(Ab + (size_t)(r0 + 16) * K + k0 + cb, lA + wave * 1024 + 512);
    glds16(Bb + (size_t)r0 * K + k0 + cb, lB + wave * 1024);
    glds16(Bb + (size_t)(r0 + 16) * K + k0 + cb, lB + wave * 1024 + 512);
    __syncthreads();
    bf16x8 af[4], bfr[4];
#pragma unroll
    for (int t = 0; t < 4; t++) {
      af[t] = *(const bf16x8*)(lA + (wm * 64 + t * 16 + m_lane) * 32 + quad * 8);
      bfr[t] = *(const bf16x8*)(lB + (wn * 64 + t * 16 + m_lane) * 32 + quad * 8);
    }
#pragma unroll
    for (int mt = 0; mt < 4; mt++)
#pragma unroll
      for (int nt = 0; nt < 4; nt++)
        acc[mt][nt] = __builtin_amdgcn_mfma_f32_16x16x32_bf16(af[mt], bfr[nt], acc[mt][nt], 0, 0, 0);
    __syncthreads();
  }

#pragma unroll
  for (int mt = 0; mt < 4; mt++) {
#pragma unroll
    for (int nt = 0; nt < 4; nt++) {
      int col = j0 + wn * 64 + nt * 16 + m_lane;
#pragma unroll
      for (int r = 0; r < 4; r++) {
        int row = i0 + wm * 64 + mt * 16 + quad * 4 + r;
        epi_one(mode, acc[mt][nt][r], row, col, ldc, C0p, C1p, C2p, C3p, bias0, bias1, res0);
      }
    }
  }
}

// ---------------- 64x128-tile GEMM variant (for N=1024 outputs: 2x the workgroups) ----------------
// 4 waves 1x4, each wave 64x32 via 4x2 mfma.
__global__ __launch_bounds__(256) void gemm_bt64(const u16* __restrict__ A,
                                                 const u16* __restrict__ Bt,
                                                 int M, int N, int K,
                                                 void* __restrict__ C0p, void* __restrict__ C1p,
                                                 void* __restrict__ C2p, void* __restrict__ C3p,
                                                 const float* __restrict__ bias0,
                                                 const float* __restrict__ bias1,
                                                 const float* __restrict__ res0,
                                                 int ldc, int mode) {
  __shared__ u16 lA[64 * 32];
  __shared__ u16 lB[128 * 32];
  const int tid = threadIdx.x;
  const int wave = tid >> 6, lane = tid & 63;
  const int i0 = blockIdx.y * 64, j0 = blockIdx.x * 128;
  const int m_lane = lane & 15, quad = lane >> 4;

  f32x4 acc[4][2] = {};

  const u16* Ab = A + (size_t)i0 * K;
  const u16* Bb = Bt + (size_t)j0 * K;
  const int rA = wave * 16 + (lane >> 2);
  const int rB = wave * 32 + (lane >> 2);
  const int cb = (lane & 3) * 8;

  for (int k0 = 0; k0 < K; k0 += 32) {
    glds16(Ab + (size_t)rA * K + k0 + cb, lA + wave * 512);
    glds16(Bb + (size_t)rB * K + k0 + cb, lB + wave * 1024);
    glds16(Bb + (size_t)(rB + 16) * K + k0 + cb, lB + wave * 1024 + 512);
    __syncthreads();
    bf16x8 af[4], bfr[2];
#pragma unroll
    for (int t = 0; t < 4; t++)
      af[t] = *(const bf16x8*)(lA + (t * 16 + m_lane) * 32 + quad * 8);
#pragma unroll
    for (int t = 0; t < 2; t++)
      bfr[t] = *(const bf16x8*)(lB + (wave * 32 + t * 16 + m_lane) * 32 + quad * 8);
#pragma unroll
    for (int mt = 0; mt < 4; mt++)
#pragma unroll
      for (int nt = 0; nt < 2; nt++)
        acc[mt][nt] = __builtin_amdgcn_mfma_f32_16x16x32_bf16(af[mt], bfr[nt], acc[mt][nt], 0, 0, 0);
    __syncthreads();
  }

#pragma unroll
  for (int mt = 0; mt < 4; mt++) {
#pragma unroll
    for (int nt = 0; nt < 2; nt++) {
      int col = j0 + wave * 32 + nt * 16 + m_lane;
#pragma unroll
      for (int r = 0; r < 4; r++) {
        int row = i0 + mt * 16 + quad * 4 + r;
        epi_one(mode, acc[mt][nt][r], row, col, ldc, C0p, C1p, C2p, C3p, bias0, bias1, res0);
      }
    }
  }
}

// ---------------- batched attention GEMM, 64x64 tile ----------------
// mode 0 (AC):  C[i,j]  = sum_d qu[i,d]*k[j,d]      (skip tj>ti)
// mode 1 (BD):  C[i, i+t-(S-1)] += sum_d qv[i,d]*r[t,d]   (skip ti+tj<15, j>=0 guard)
// mode 2 (AV):  o[i,d]  = sum_j aw[i,j]*vT[d,j]     (bf16 out; K clipped causally)
__global__ __launch_bounds__(256) void attn_gemm(const u16* __restrict__ A, int lda,
                                                 const u16* __restrict__ Bt, int ldb,
                                                 float* __restrict__ Cf, u16* __restrict__ Cb,
                                                 int K, int mode) {
  const int ti = blockIdx.x, tj = blockIdx.y, bh = blockIdx.z;
  if (mode == 0 && tj > ti) return;
  if (mode == 1 && ti + tj < 15) return;
  const int b = bh >> 4, h = bh & 15;
  __shared__ u16 lA[64 * 64];
  __shared__ u16 lB[64 * 64];
  const int tid = threadIdx.x, wave = tid >> 6, lane = tid & 63;
  const int m_lane = lane & 15, quad = lane >> 4;
  const int i0 = ti * 64, j0 = tj * 64;

  size_t aoff, boff;
  if (mode == 0)      { aoff = (size_t)b * S_ * D_ + h * DH_; boff = (size_t)b * S_ * D_ + h * DH_; }
  else if (mode == 1) { aoff = (size_t)b * S_ * D_ + h * DH_; boff = (size_t)h * DH_; }
  else                { aoff = (size_t)bh * S_ * S_;          boff = (size_t)bh * DH_ * S_; }
  const u16* Ap = A + aoff + (size_t)i0 * lda;
  const u16* Bp = Bt + boff + (mode == 2 ? (size_t)0 : (size_t)j0 * ldb);

  f32x4 acc[4] = {};
  const int cid0 = wave * 128 + lane, cid1 = cid0 + 64;
  const int ar0 = cid0 >> 3, ac0 = (cid0 & 7) * 8;
  const int ar1 = cid1 >> 3, ac1 = (cid1 & 7) * 8;

  const int Kend = (mode == 2) ? (ti + 1) * 64 : K;   // causal clip for AV
  for (int k0 = 0; k0 < Kend; k0 += 64) {
    glds16(Ap + (size_t)ar0 * lda + k0 + ac0, lA + wave * 1024);
    glds16(Ap + (size_t)ar1 * lda + k0 + ac1, lA + wave * 1024 + 512);
    glds16(Bp + (size_t)ar0 * ldb + k0 + ac0, lB + wave * 1024);
    glds16(Bp + (size_t)ar1 * ldb + k0 + ac1, lB + wave * 1024 + 512);
    __syncthreads();
    bf16x8 a0 = *(const bf16x8*)(lA + (wave * 16 + m_lane) * 64 + quad * 8);
    bf16x8 a1 = *(const bf16x8*)(lA + (wave * 16 + m_lane) * 64 + 32 + quad * 8);
#pragma unroll
    for (int nt = 0; nt < 4; nt++) {
      bf16x8 b0 = *(const bf16x8*)(lB + (nt * 16 + m_lane) * 64 + quad * 8);
      bf16x8 b1 = *(const bf16x8*)(lB + (nt * 16 + m_lane) * 64 + 32 + quad * 8);
      acc[nt] = __builtin_amdgcn_mfma_f32_16x16x32_bf16(a0, b0, acc[nt], 0, 0, 0);
      acc[nt] = __builtin_amdgcn_mfma_f32_16x16x32_bf16(a1, b1, acc[nt], 0, 0, 0);
    }
    __syncthreads();
  }

  if (mode == 0) {
    float* C = Cf + (size_t)bh * S_ * S_;
#pragma unroll
    for (int nt = 0; nt < 4; nt++) {
      int col = j0 + nt * 16 + m_lane;
#pragma unroll
      for (int r = 0; r < 4; r++) {
        int row = i0 + wave * 16 + quad * 4 + r;
        C[(size_t)row * S_ + col] = acc[nt][r];
      }
    }
  } else if (mode == 1) {
    float* C = Cf + (size_t)bh * S_ * S_;
#pragma unroll
    for (int nt = 0; nt < 4; nt++) {
      int t = j0 + nt * 16 + m_lane;
#pragma unroll
      for (int r = 0; r < 4; r++) {
        int row = i0 + wave * 16 + quad * 4 + r;
        int j = row + t - (S_ - 1);
        if (j >= 0) C[(size_t)row * S_ + j] += acc[nt][r];
      }
    }
  } else {
    u16* C = Cb + (size_t)b * S_ * D_ + h * DH_;
#pragma unroll
    for (int nt = 0; nt < 4; nt++) {
      int col = nt * 16 + m_lane;  // d
#pragma unroll
      for (int r = 0; r < 4; r++) {
        int row = i0 + wave * 16 + quad * 4 + r;
        C[(size_t)row * D_ + col] = f2bf(acc[nt][r]);
      }
    }
  }
}

// ---------------- softmax over causal row: single-pass float4, tile-clipped store ----------------
__global__ __launch_bounds__(256) void softmax_k(const float* __restrict__ scores,
                                                 u16* __restrict__ aw,
                                                 const int* __restrict__ text) {
  const int i = blockIdx.x, bh = blockIdx.y, b = bh >> 4;
  const float* s = scores + ((size_t)bh * S_ + i) * S_;
  u16* o = aw + ((size_t)bh * S_ + i) * S_;
  const int tid = threadIdx.x, wave = tid >> 6, lane = tid & 63;
  const int n = i + 1;
  const int jmax = ((i >> 6) + 1) << 6;   // AV reads only j < jmax for this row's tile
  const int j0 = tid * 4;
  if (text[b * CTX_ + i] == PAD_) {       // fully-masked query row -> aw = 0
    if (j0 < jmax) ((ushort4*)o)[tid] = make_ushort4(0, 0, 0, 0);
    return;
  }
  const float scale = 0.125f;             // 1/sqrt(64)
  float4 sv = ((const float4*)s)[tid];
  float e0 = (j0 + 0 < n) ? sv.x * scale : -3e38f;
  float e1 = (j0 + 1 < n) ? sv.y * scale : -3e38f;
  float e2 = (j0 + 2 < n) ? sv.z * scale : -3e38f;
  float e3 = (j0 + 3 < n) ? sv.w * scale : -3e38f;
  float mx = fmaxf(fmaxf(e0, e1), fmaxf(e2, e3));
  __shared__ float red[8];
#pragma unroll
  for (int off = 32; off > 0; off >>= 1) mx = fmaxf(mx, __shfl_xor(mx, off));
  if (lane == 0) red[wave] = mx;
  __syncthreads();
  mx = fmaxf(fmaxf(red[0], red[1]), fmaxf(red[2], red[3]));
  float p0 = __expf(e0 - mx);   // masked lanes: exp(-inf) = 0
  float p1 = __expf(e1 - mx);
  float p2 = __expf(e2 - mx);
  float p3 = __expf(e3 - mx);
  float sum = p0 + p1 + p2 + p3;
#pragma unroll
  for (int off = 32; off > 0; off >>= 1) sum += __shfl_xor(sum, off);
  if (lane == 0) red[4 + wave] = sum;
  __syncthreads();
  sum = red[4] + red[5] + red[6] + red[7];
  float inv = 1.0f / sum;
  if (j0 < jmax)
    ((ushort4*)o)[tid] = make_ushort4(f2bf(p0 * inv), f2bf(p1 * inv), f2bf(p2 * inv), f2bf(p3 * inv));
}

// ---------------- v transpose: (B*S, D) -> (B,H,DH,S) ----------------
__global__ __launch_bounds__(256) void v_transpose(const u16* __restrict__ v,
                                                   u16* __restrict__ vT) {
  int bh = blockIdx.y, b = bh >> 4, h = bh & 15;
  int j0 = blockIdx.x * 64;
  __shared__ u16 tile[64][65];
  for (int idx = threadIdx.x; idx < 4096; idx += 256) {
    int jj = idx >> 6, d = idx & 63;
    tile[jj][d] = v[(size_t)(b * S_ + j0 + jj) * D_ + h * DH_ + d];
  }
  __syncthreads();
  for (int idx = threadIdx.x; idx < 4096; idx += 256) {
    int d = idx >> 6, jj = idx & 63;
    vT[((size_t)bh * DH_ + d) * S_ + j0 + jj] = tile[jj][d];
  }
}

// =====================================================================
extern "C" void kernel_launch(void* const* d_in, const int* in_sizes, int n_in,
                              void* d_out, int out_size, void* d_ws, size_t ws_size,
                              hipStream_t stream) {
  (void)in_sizes; (void)n_in; (void)out_size;
  const int* text = (const int*)d_in[0];
  const float* emb = (const float*)d_in[1];
  const float* u_in = (const float*)d_in[2];
  const float* v_in = (const float*)d_in[3];
  const float* Wq = (const float*)d_in[4];
  const float* Wk = (const float*)d_in[5];
  const float* Wv = (const float*)d_in[6];
  const float* Wr = (const float*)d_in[7];
  const float* Wfc = (const float*)d_in[8];
  const float* bfc = (const float*)d_in[9];
  const float* ln1g = (const float*)d_in[10];
  const float* ln1b = (const float*)d_in[11];
  const float* ln2g = (const float*)d_in[12];
  const float* ln2b = (const float*)d_in[13];
  const float* W1 = (const float*)d_in[14];
  const float* b1 = (const float*)d_in[15];
  const float* W2 = (const float*)d_in[16];
  const float* b2 = (const float*)d_in[17];
  const float* lnfg = (const float*)d_in[18];
  const float* lnfb = (const float*)d_in[19];
  const float* Wlm = (const float*)d_in[20];
  const float* blm = (const float*)d_in[21];
  float* out = (float*)d_out;

  char* w = (char*)d_ws;
  size_t off = 0;
  auto alloc = [&](size_t bytes) -> void* {
    void* p = w + off;
    off += (bytes + 255) & ~(size_t)255;
    return p;
  };
  float* x      = (float*)alloc(2048ull * 1024 * 4);
  float* xnf    = (float*)alloc(2048ull * 1024 * 4);
  u16* xnb      = (u16*)alloc(2048ull * 1024 * 2);
  u16* relb     = (u16*)alloc(1024ull * 1024 * 2);
  u16* wqkvt    = (u16*)alloc(3072ull * 1024 * 2);   // [Wq^T | Wk^T | Wv^T]
  u16* wrt_all  = (u16*)alloc(4096ull * 1024 * 2);   // all 4 layers' Wr^T
  u16* wfct     = (u16*)alloc(1024ull * 1024 * 2);
  u16* w1t      = (u16*)alloc(4096ull * 1024 * 2);
  u16* w2t      = (u16*)alloc(4096ull * 1024 * 2);
  u16* wlmt     = (u16*)alloc(32000ull * 1024 * 2);
  u16* qu       = (u16*)alloc(2048ull * 1024 * 2);
  u16* qv       = (u16*)alloc(2048ull * 1024 * 2);
  u16* kk       = (u16*)alloc(2048ull * 1024 * 2);
  u16* vv       = (u16*)alloc(2048ull * 1024 * 2);
  u16* vT       = (u16*)alloc(2048ull * 1024 * 2);
  u16* rb_all   = (u16*)alloc(1024ull * 4096 * 2);   // rel @ Wr[l], all layers (ldc=4096)
  float* scores = (float*)alloc(32ull * 1024 * 1024 * 4);
  u16* aw       = (u16*)alloc(32ull * 1024 * 1024 * 2);
  u16* o_       = (u16*)alloc(2048ull * 1024 * 2);
  u16* f1       = (u16*)alloc(2048ull * 4096 * 2);
  if (off > ws_size) return;  // workspace too small; fail loudly via wrong output

  dim3 blk(256);
  embed_gather<<<2048, blk, 0, stream>>>(text, emb, x);
  rel_enc<<<1024, blk, 0, stream>>>(relb);
  wconv_t<<<dim3(1000, 32), blk, 0, stream>>>(Wlm, wlmt, 1024, 32000);
  // all 4 layers' Wr^T, then one batched R projection: rb_all = rel @ [Wr0|Wr1|Wr2|Wr3]
  wconv_t<<<dim3(32, 32, 4), blk, 0, stream>>>(Wr, wrt_all, 1024, 1024);
  gemm_bt<<<dim3(32, 8), blk, 0, stream>>>(relb, wrt_all, 1024, 4096, 1024,
                                           rb_all, nullptr, nullptr, nullptr,
                                           nullptr, nullptr, nullptr, 4096, EPI_BF16);

  for (int l = 0; l < 4; l++) {
    const size_t dd = 1048576;  // D*D
    wconv4_k<<<dim3(32, 32, 4), blk, 0, stream>>>(Wq + l * dd, Wk + l * dd, Wv + l * dd,
                                                  Wfc + l * dd, wqkvt, wfct);
    wconv_t<<<dim3(128, 32), blk, 0, stream>>>(W1 + l * 4ull * dd, w1t, 1024, 4096);
    wconv_t<<<dim3(32, 128), blk, 0, stream>>>(W2 + l * 4ull * dd, w2t, 4096, 1024);

    layernorm_k<<<2048, blk, 0, stream>>>(x, ln1g + l * 1024, ln1b + l * 1024, xnf, xnb);

    // fused Q/K/V projection: N=3072, 384 workgroups
    gemm_bt<<<dim3(24, 16), blk, 0, stream>>>(xnb, wqkvt, 2048, 3072, 1024,
                                              qu, qv, kk, vv, u_in, v_in, nullptr, 1024, EPI_QKV);
    v_transpose<<<dim3(16, 32), blk, 0, stream>>>(vv, vT);

    attn_gemm<<<dim3(16, 16, 32), blk, 0, stream>>>(qu, 1024, kk, 1024, scores, nullptr, 64, 0);
    attn_gemm<<<dim3(16, 16, 32), blk, 0, stream>>>(qv, 1024, rb_all + (size_t)l * 1024, 4096,
                                                    scores, nullptr, 64, 1);
    softmax_k<<<dim3(1024, 32), blk, 0, stream>>>(scores, aw, text);
    attn_gemm<<<dim3(16, 1, 32), blk, 0, stream>>>(aw, 1024, vT, 1024, nullptr, o_, 1024, 2);

    gemm_bt64<<<dim3(8, 32), blk, 0, stream>>>(o_, wfct, 2048, 1024, 1024,
                                               x, nullptr, nullptr, nullptr,
                                               bfc + l * 1024, nullptr, xnf, 1024, EPI_FC);
    layernorm_k<<<2048, blk, 0, stream>>>(x, ln2g + l * 1024, ln2b + l * 1024, nullptr, xnb);
    gemm_bt<<<dim3(32, 16), blk, 0, stream>>>(xnb, w1t, 2048, 4096, 1024,
                                              f1, nullptr, nullptr, nullptr,
                                              b1 + l * 4096, nullptr, nullptr, 4096, EPI_GELU_BF16);
    gemm_bt64<<<dim3(8, 32), blk, 0, stream>>>(f1, w2t, 2048, 1024, 4096,
                                               x, nullptr, nullptr, nullptr,
                                               b2 + l * 1024, nullptr, nullptr, 1024, EPI_GELU_RES);
  }

  layernorm_k<<<2048, blk, 0, stream>>>(x, lnfg, lnfb, nullptr, xnb);
  gemm_bt<<<dim3(250, 16), blk, 0, stream>>>(xnb, wlmt, 2048, 32000, 1024,
                                             out, nullptr, nullptr, nullptr,
                                             blm, nullptr, nullptr, 32000, EPI_BIAS_F32);
}

// Round 3
// 2348.883 us; speedup vs baseline: 1.0304x; 1.0304x over previous
//
#include <hip/hip_runtime.h>
#include <stdint.h>

#define S_ 1024
#define D_ 1024
#define H_ 16
#define DH_ 64
#define FF_ 4096
#define B_ 2
#define V_ 32000
#define CTX_ 1025
#define PAD_ 3

typedef unsigned short u16;
typedef __attribute__((ext_vector_type(8))) short bf16x8;
typedef __attribute__((ext_vector_type(4))) float f32x4;

enum { EPI_BF16 = 0, EPI_QKV = 1, EPI_FC = 2, EPI_GELU_BF16 = 3, EPI_GELU_RES = 4, EPI_BIAS_F32 = 5 };

__device__ __forceinline__ u16 f2bf(float f) {
  unsigned u = __float_as_uint(f);
  return (u16)((u + 0x7FFFu + ((u >> 16) & 1u)) >> 16);
}

__device__ __forceinline__ float bf2f(u16 v) {
  return __uint_as_float(((unsigned)v) << 16);
}

__device__ __forceinline__ float gelu_f(float x) {
  float t = tanhf(0.7978845608028654f * (x + 0.044715f * x * x * x));
  return 0.5f * x * (1.0f + t);
}

__device__ __forceinline__ void glds16(const void* g, void* l) {
  __builtin_amdgcn_global_load_lds(
      (const __attribute__((address_space(1))) unsigned int*)g,
      (__attribute__((address_space(3))) unsigned int*)l,
      16, 0, 0);
}

// ---------------- embedding gather ----------------
__global__ __launch_bounds__(256) void embed_gather(const int* __restrict__ text,
                                                    const float* __restrict__ emb,
                                                    float* __restrict__ x) {
  int row = blockIdx.x;             // 0..2047  (b*1024 + s)
  int b = row >> 10, s = row & 1023;
  int id = text[b * CTX_ + s];
  float4 v = ((const float4*)(emb + (size_t)id * D_))[threadIdx.x];
  ((float4*)(x + (size_t)row * D_))[threadIdx.x] = v;
}

// ---------------- relative positional encoding (bf16) ----------------
__global__ __launch_bounds__(256) void rel_enc(u16* __restrict__ rel) {
  int i = blockIdx.x;               // 0..1023
  float pos = (float)(S_ - 1 - i);
  for (int t = threadIdx.x; t < 512; t += 256) {
    float invf = exp2f(-(float)t * (13.287712379549449f / 512.0f)); // 10000^(-t/512)
    float ang = pos * invf;
    rel[(size_t)i * D_ + t] = f2bf(sinf(ang));
    rel[(size_t)i * D_ + 512 + t] = f2bf(cosf(ang));
  }
}

// ---------------- weight convert f32 (K,N) -> bf16 (N,K), z-batched ----------------
__global__ __launch_bounds__(256) void wconv_t(const float* __restrict__ src,
                                               u16* __restrict__ dst, int K, int N) {
  src += (size_t)blockIdx.z * K * N;
  dst += (size_t)blockIdx.z * K * N;
  __shared__ float tile[32][33];
  int n0 = blockIdx.x * 32, k0 = blockIdx.y * 32;
  for (int idx = threadIdx.x; idx < 1024; idx += 256) {
    int r = idx >> 5, c = idx & 31;                 // r: k, c: n
    tile[r][c] = src[(size_t)(k0 + r) * N + n0 + c];
  }
  __syncthreads();
  for (int idx = threadIdx.x; idx < 1024; idx += 256) {
    int r = idx >> 5, c = idx & 31;                 // r: n, c: k
    dst[(size_t)(n0 + r) * K + k0 + c] = f2bf(tile[c][r]);
  }
}

// ---------------- 4-way weight convert (Wq,Wk,Wv -> qkv segments; Wfc -> fc) ----------------
__global__ __launch_bounds__(256) void wconv4_k(const float* __restrict__ sq,
                                                const float* __restrict__ sk,
                                                const float* __restrict__ sv,
                                                const float* __restrict__ sf,
                                                u16* __restrict__ dqkv,
                                                u16* __restrict__ dfc) {
  const int z = blockIdx.z;
  const float* src = (z == 0) ? sq : (z == 1) ? sk : (z == 2) ? sv : sf;
  u16* dst = (z < 3) ? dqkv + (size_t)z * 1024 * 1024 : dfc;
  __shared__ float tile[32][33];
  int n0 = blockIdx.x * 32, k0 = blockIdx.y * 32;
  for (int idx = threadIdx.x; idx < 1024; idx += 256) {
    int r = idx >> 5, c = idx & 31;
    tile[r][c] = src[(size_t)(k0 + r) * 1024 + n0 + c];
  }
  __syncthreads();
  for (int idx = threadIdx.x; idx < 1024; idx += 256) {
    int r = idx >> 5, c = idx & 31;
    dst[(size_t)(n0 + r) * 1024 + k0 + c] = f2bf(tile[c][r]);
  }
}

// ---------------- layernorm (block per row) ----------------
__global__ __launch_bounds__(256) void layernorm_k(const float* __restrict__ x,
                                                   const float* __restrict__ g,
                                                   const float* __restrict__ bb,
                                                   float* __restrict__ outf,
                                                   u16* __restrict__ outb) {
  int row = blockIdx.x, tid = threadIdx.x;
  const float* xr = x + (size_t)row * D_;
  float4 v = ((const float4*)xr)[tid];
  float s = v.x + v.y + v.z + v.w;
  float s2 = v.x * v.x + v.y * v.y + v.z * v.z + v.w * v.w;
  __shared__ float red[8];
#pragma unroll
  for (int off = 32; off > 0; off >>= 1) { s += __shfl_xor(s, off); s2 += __shfl_xor(s2, off); }
  if ((tid & 63) == 0) { red[tid >> 6] = s; red[4 + (tid >> 6)] = s2; }
  __syncthreads();
  s = red[0] + red[1] + red[2] + red[3];
  s2 = red[4] + red[5] + red[6] + red[7];
  float mean = s * (1.0f / D_);
  float var = s2 * (1.0f / D_) - mean * mean;
  float rstd = rsqrtf(var + 1e-5f);
  float4 gv = ((const float4*)g)[tid];
  float4 bv = ((const float4*)bb)[tid];
  float y0 = (v.x - mean) * rstd * gv.x + bv.x;
  float y1 = (v.y - mean) * rstd * gv.y + bv.y;
  float y2 = (v.z - mean) * rstd * gv.z + bv.z;
  float y3 = (v.w - mean) * rstd * gv.w + bv.w;
  if (outf) ((float4*)(outf + (size_t)row * D_))[tid] = make_float4(y0, y1, y2, y3);
  ((ushort4*)(outb + (size_t)row * D_))[tid] = make_ushort4(f2bf(y0), f2bf(y1), f2bf(y2), f2bf(y3));
}

// ---------------- shared GEMM epilogue ----------------
__device__ __forceinline__ void epi_one(int mode, float v, int row, int col, int ldc,
                                        void* C0p, void* C1p, void* C2p, void* C3p,
                                        const float* bias0, const float* bias1,
                                        const float* res0) {
  if (mode == EPI_QKV) {
    // cols [0,1024): Q -> qu=q+u, qv=q+v ; [1024,2048): K ; [2048,3072): V
    int seg = col >> 10, c = col & 1023;
    size_t idx = (size_t)row * 1024 + c;
    if (seg == 0) {
      ((u16*)C0p)[idx] = f2bf(v + bias0[c]);
      ((u16*)C1p)[idx] = f2bf(v + bias1[c]);
    } else if (seg == 1) {
      ((u16*)C2p)[idx] = f2bf(v);
    } else {
      ((u16*)C3p)[idx] = f2bf(v);
    }
    return;
  }
  size_t idx = (size_t)row * ldc + col;
  float b0 = bias0 ? bias0[col] : 0.0f;
  if (mode == EPI_BF16) {
    ((u16*)C0p)[idx] = f2bf(v);
  } else if (mode == EPI_FC) {
    float* C0 = (float*)C0p;
    C0[idx] = C0[idx] + v + b0 + res0[idx];
  } else if (mode == EPI_GELU_BF16) {
    ((u16*)C0p)[idx] = f2bf(gelu_f(v + b0));
  } else if (mode == EPI_GELU_RES) {
    float* C0 = (float*)C0p;
    C0[idx] = C0[idx] + gelu_f(v + b0);
  } else { // EPI_BIAS_F32
    ((float*)C0p)[idx] = v + b0;
  }
}

// ---------------- main GEMM: C(M,N) = A(M,K) @ Bt(N,K)^T ----------------
// 128x128 tile, BK=32, 4 waves (2x2), each wave 64x64 via 4x4 mfma_f32_16x16x32_bf16.
// XCD-aware swizzle, COLUMN clustering: each XCD owns a contiguous slab of column
// tiles x all row tiles -> B (the big operand: Wlm 65MB) fetched once chip-wide,
// A stays resident in the XCD's 4MB L2.
__global__ __launch_bounds__(256) void gemm_bt(const u16* __restrict__ A,
                                               const u16* __restrict__ Bt,
                                               int M, int N, int K,
                                               void* __restrict__ C0p, void* __restrict__ C1p,
                                               void* __restrict__ C2p, void* __restrict__ C3p,
                                               const float* __restrict__ bias0,
                                               const float* __restrict__ bias1,
                                               const float* __restrict__ res0,
                                               int ldc, int mode) {
  __shared__ u16 lA[128 * 32];
  __shared__ u16 lB[128 * 32];
  const int tid = threadIdx.x;
  const int wave = tid >> 6, lane = tid & 63;
  unsigned gx = gridDim.x, gy = gridDim.y;
  unsigned nwg = gx * gy;
  unsigned bx = blockIdx.x, by = blockIdx.y;
  if ((nwg & 7u) == 0u) {
    unsigned lin = by * gx + bx;
    unsigned v = (lin & 7u) * (nwg >> 3) + (lin >> 3);
    bx = v / gy;            // column tile (consecutive v share a column)
    by = v - bx * gy;       // row tile
  }
  const int i0 = by * 128, j0 = bx * 128;
  const int wm = wave & 1, wn = wave >> 1;
  const int m_lane = lane & 15, quad = lane >> 4;

  f32x4 acc[4][4] = {};

  const u16* Ab = A + (size_t)i0 * K;
  const u16* Bb = Bt + (size_t)j0 * K;
  const int r0 = wave * 32 + (lane >> 2);
  const int cb = (lane & 3) * 8;

  for (int k0 = 0; k0 < K; k0 += 32) {
    glds16(Ab + (size_t)r0 * K + k0 + cb, lA + wave * 1024);
    glds16(Ab + (size_t)(r0 + 16) * K + k0 + cb, lA + wave * 1024 + 512);
    glds16(Bb + (size_t)r0 * K + k0 + cb, lB + wave * 1024);
    glds16(Bb + (size_t)(r0 + 16) * K + k0 + cb, lB + wave * 1024 + 512);
    __syncthreads();
    bf16x8 af[4], bfr[4];
#pragma unroll
    for (int t = 0; t < 4; t++) {
      af[t] = *(const bf16x8*)(lA + (wm * 64 + t * 16 + m_lane) * 32 + quad * 8);
      bfr[t] = *(const bf16x8*)(lB + (wn * 64 + t * 16 + m_lane) * 32 + quad * 8);
    }
#pragma unroll
    for (int mt = 0; mt < 4; mt++)
#pragma unroll
      for (int nt = 0; nt < 4; nt++)
        acc[mt][nt] = __builtin_amdgcn_mfma_f32_16x16x32_bf16(af[mt], bfr[nt], acc[mt][nt], 0, 0, 0);
    __syncthreads();
  }

#pragma unroll
  for (int mt = 0; mt < 4; mt++) {
#pragma unroll
    for (int nt = 0; nt < 4; nt++) {
      int col = j0 + wn * 64 + nt * 16 + m_lane;
#pragma unroll
      for (int r = 0; r < 4; r++) {
        int row = i0 + wm * 64 + mt * 16 + quad * 4 + r;
        epi_one(mode, acc[mt][nt][r], row, col, ldc, C0p, C1p, C2p, C3p, bias0, bias1, res0);
      }
    }
  }
}

// ---------------- 64x128-tile GEMM variant (for N=1024 outputs) ----------------
// ROW clustering swizzle (A is the big operand for ff2: f1 = 16.8MB vs B 8.4MB).
__global__ __launch_bounds__(256) void gemm_bt64(const u16* __restrict__ A,
                                                 const u16* __restrict__ Bt,
                                                 int M, int N, int K,
                                                 void* __restrict__ C0p, void* __restrict__ C1p,
                                                 void* __restrict__ C2p, void* __restrict__ C3p,
                                                 const float* __restrict__ bias0,
                                                 const float* __restrict__ bias1,
                                                 const float* __restrict__ res0,
                                                 int ldc, int mode) {
  __shared__ u16 lA[64 * 32];
  __shared__ u16 lB[128 * 32];
  const int tid = threadIdx.x;
  const int wave = tid >> 6, lane = tid & 63;
  unsigned gx = gridDim.x, gy = gridDim.y;
  unsigned nwg = gx * gy;
  unsigned bx = blockIdx.x, by = blockIdx.y;
  if ((nwg & 7u) == 0u) {
    unsigned lin = by * gx + bx;
    unsigned v = (lin & 7u) * (nwg >> 3) + (lin >> 3);
    by = v / gx;            // row tile (consecutive v share a row)
    bx = v - by * gx;       // column tile
  }
  const int i0 = by * 64, j0 = bx * 128;
  const int m_lane = lane & 15, quad = lane >> 4;

  f32x4 acc[4][2] = {};

  const u16* Ab = A + (size_t)i0 * K;
  const u16* Bb = Bt + (size_t)j0 * K;
  const int rA = wave * 16 + (lane >> 2);
  const int rB = wave * 32 + (lane >> 2);
  const int cb = (lane & 3) * 8;

  for (int k0 = 0; k0 < K; k0 += 32) {
    glds16(Ab + (size_t)rA * K + k0 + cb, lA + wave * 512);
    glds16(Bb + (size_t)rB * K + k0 + cb, lB + wave * 1024);
    glds16(Bb + (size_t)(rB + 16) * K + k0 + cb, lB + wave * 1024 + 512);
    __syncthreads();
    bf16x8 af[4], bfr[2];
#pragma unroll
    for (int t = 0; t < 4; t++)
      af[t] = *(const bf16x8*)(lA + (t * 16 + m_lane) * 32 + quad * 8);
#pragma unroll
    for (int t = 0; t < 2; t++)
      bfr[t] = *(const bf16x8*)(lB + (wave * 32 + t * 16 + m_lane) * 32 + quad * 8);
#pragma unroll
    for (int mt = 0; mt < 4; mt++)
#pragma unroll
      for (int nt = 0; nt < 2; nt++)
        acc[mt][nt] = __builtin_amdgcn_mfma_f32_16x16x32_bf16(af[mt], bfr[nt], acc[mt][nt], 0, 0, 0);
    __syncthreads();
  }

#pragma unroll
  for (int mt = 0; mt < 4; mt++) {
#pragma unroll
    for (int nt = 0; nt < 2; nt++) {
      int col = j0 + wave * 32 + nt * 16 + m_lane;
#pragma unroll
      for (int r = 0; r < 4; r++) {
        int row = i0 + mt * 16 + quad * 4 + r;
        epi_one(mode, acc[mt][nt][r], row, col, ldc, C0p, C1p, C2p, C3p, bias0, bias1, res0);
      }
    }
  }
}

// ---------------- fused attention score: AC + rel-shifted BD, one pass ----------------
// grid (136, 32): blockIdx.x = causal tile index c -> (ti,tj) with tj<=ti,
// blockIdx.y = bh. Writes scores[i][j] = qu_i.k_j + qv_i.r_{j-i+1023} (unscaled).
// BD needs r-tiles T0=15-(ti-tj) and T0+1 (t offsets 0..126 across the tile);
// routed through a padded bf16 LDS tile for the diagonal gather.
__global__ __launch_bounds__(256) void attn_score(const u16* __restrict__ qu,
                                                  const u16* __restrict__ qv,
                                                  const u16* __restrict__ kk,
                                                  const u16* __restrict__ rb, // + l*1024, row stride 4096
                                                  float* __restrict__ scores) {
  __shared__ u16 sBD[64][132];   // +4 pad: quad rows shift banks by 8 -> conflict-free
  const int cIdx = blockIdx.x, bh = blockIdx.y;
  int ti = (int)((sqrtf(8.0f * (float)cIdx + 1.0f) - 1.0f) * 0.5f);
  while ((ti + 1) * (ti + 2) / 2 <= cIdx) ti++;
  while (ti * (ti + 1) / 2 > cIdx) ti--;
  const int tj = cIdx - ti * (ti + 1) / 2;
  const int b = bh >> 4, h = bh & 15;
  const int tid = threadIdx.x, wave = tid >> 6, lane = tid & 63;
  const int m_lane = lane & 15, quad = lane >> 4;
  const int i0 = ti * 64, j0 = tj * 64;
  const int T0 = 15 - (ti - tj);
  const bool hasT1 = (T0 < 15);

  // A fragments direct from global (rows i0+wave*16+m_lane, cols h*64+quad*8)
  const u16* Qu = qu + ((size_t)(b * S_ + i0 + wave * 16 + m_lane)) * D_ + h * DH_ + quad * 8;
  const u16* Qv = qv + ((size_t)(b * S_ + i0 + wave * 16 + m_lane)) * D_ + h * DH_ + quad * 8;
  bf16x8 a0 = *(const bf16x8*)(Qu);
  bf16x8 a1 = *(const bf16x8*)(Qu + 32);
  bf16x8 c0 = *(const bf16x8*)(Qv);
  bf16x8 c1 = *(const bf16x8*)(Qv + 32);

  const u16* Kb = kk + ((size_t)(b * S_ + j0)) * D_ + h * DH_;
  const u16* R0 = rb + ((size_t)(T0 * 64)) * 4096 + h * DH_;
  const u16* R1 = R0 + (size_t)64 * 4096;

  f32x4 ac_[4] = {}, bd0_[4] = {}, bd1_[4] = {};
#pragma unroll
  for (int nt = 0; nt < 4; nt++) {
    const u16* kr = Kb + (size_t)(nt * 16 + m_lane) * D_ + quad * 8;
    bf16x8 kb0 = *(const bf16x8*)(kr);
    bf16x8 kb1 = *(const bf16x8*)(kr + 32);
    ac_[nt] = __builtin_amdgcn_mfma_f32_16x16x32_bf16(a0, kb0, ac_[nt], 0, 0, 0);
    ac_[nt] = __builtin_amdgcn_mfma_f32_16x16x32_bf16(a1, kb1, ac_[nt], 0, 0, 0);
    const u16* rr = R0 + (size_t)(nt * 16 + m_lane) * 4096 + quad * 8;
    bf16x8 rb0 = *(const bf16x8*)(rr);
    bf16x8 rb1 = *(const bf16x8*)(rr + 32);
    bd0_[nt] = __builtin_amdgcn_mfma_f32_16x16x32_bf16(c0, rb0, bd0_[nt], 0, 0, 0);
    bd0_[nt] = __builtin_amdgcn_mfma_f32_16x16x32_bf16(c1, rb1, bd0_[nt], 0, 0, 0);
    if (hasT1) {
      const u16* r2 = R1 + (size_t)(nt * 16 + m_lane) * 4096 + quad * 8;
      bf16x8 rc0 = *(const bf16x8*)(r2);
      bf16x8 rc1 = *(const bf16x8*)(r2 + 32);
      bd1_[nt] = __builtin_amdgcn_mfma_f32_16x16x32_bf16(c0, rc0, bd1_[nt], 0, 0, 0);
      bd1_[nt] = __builtin_amdgcn_mfma_f32_16x16x32_bf16(c1, rc1, bd1_[nt], 0, 0, 0);
    }
  }

  // BD (i,t) tiles -> LDS (bf16). Each wave writes/reads only its own 16 rows.
#pragma unroll
  for (int nt = 0; nt < 4; nt++) {
    int col = nt * 16 + m_lane;
#pragma unroll
    for (int r = 0; r < 4; r++) {
      int row = wave * 16 + quad * 4 + r;
      sBD[row][col] = f2bf(bd0_[nt][r]);
      sBD[row][64 + col] = hasT1 ? f2bf(bd1_[nt][r]) : (u16)0;
    }
  }
  __syncthreads();

  float* C = scores + (size_t)bh * S_ * S_ + (size_t)i0 * S_ + j0;
#pragma unroll
  for (int nt = 0; nt < 4; nt++) {
    int jl = nt * 16 + m_lane;
#pragma unroll
    for (int r = 0; r < 4; r++) {
      int il = wave * 16 + quad * 4 + r;
      int tloc = jl - il + 63;          // in [0,126]; >63 only in masked or hasT1 region
      C[(size_t)il * S_ + jl] = ac_[nt][r] + bf2f(sBD[il][tloc]);
    }
  }
}

// ---------------- batched attention GEMM (mode 2 = AV used) ----------------
__global__ __launch_bounds__(256) void attn_gemm(const u16* __restrict__ A, int lda,
                                                 const u16* __restrict__ Bt, int ldb,
                                                 float* __restrict__ Cf, u16* __restrict__ Cb,
                                                 int K, int mode) {
  const int ti = blockIdx.x, tj = blockIdx.y, bh = blockIdx.z;
  if (mode == 0 && tj > ti) return;
  if (mode == 1 && ti + tj < 15) return;
  const int b = bh >> 4, h = bh & 15;
  __shared__ u16 lA[64 * 64];
  __shared__ u16 lB[64 * 64];
  const int tid = threadIdx.x, wave = tid >> 6, lane = tid & 63;
  const int m_lane = lane & 15, quad = lane >> 4;
  const int i0 = ti * 64, j0 = tj * 64;

  size_t aoff, boff;
  if (mode == 0)      { aoff = (size_t)b * S_ * D_ + h * DH_; boff = (size_t)b * S_ * D_ + h * DH_; }
  else if (mode == 1) { aoff = (size_t)b * S_ * D_ + h * DH_; boff = (size_t)h * DH_; }
  else                { aoff = (size_t)bh * S_ * S_;          boff = (size_t)bh * DH_ * S_; }
  const u16* Ap = A + aoff + (size_t)i0 * lda;
  const u16* Bp = Bt + boff + (mode == 2 ? (size_t)0 : (size_t)j0 * ldb);

  f32x4 acc[4] = {};
  const int cid0 = wave * 128 + lane, cid1 = cid0 + 64;
  const int ar0 = cid0 >> 3, ac0 = (cid0 & 7) * 8;
  const int ar1 = cid1 >> 3, ac1 = (cid1 & 7) * 8;

  const int Kend = (mode == 2) ? (ti + 1) * 64 : K;   // causal clip for AV
  for (int k0 = 0; k0 < Kend; k0 += 64) {
    glds16(Ap + (size_t)ar0 * lda + k0 + ac0, lA + wave * 1024);
    glds16(Ap + (size_t)ar1 * lda + k0 + ac1, lA + wave * 1024 + 512);
    glds16(Bp + (size_t)ar0 * ldb + k0 + ac0, lB + wave * 1024);
    glds16(Bp + (size_t)ar1 * ldb + k0 + ac1, lB + wave * 1024 + 512);
    __syncthreads();
    bf16x8 a0 = *(const bf16x8*)(lA + (wave * 16 + m_lane) * 64 + quad * 8);
    bf16x8 a1 = *(const bf16x8*)(lA + (wave * 16 + m_lane) * 64 + 32 + quad * 8);
#pragma unroll
    for (int nt = 0; nt < 4; nt++) {
      bf16x8 b0 = *(const bf16x8*)(lB + (nt * 16 + m_lane) * 64 + quad * 8);
      bf16x8 b1 = *(const bf16x8*)(lB + (nt * 16 + m_lane) * 64 + 32 + quad * 8);
      acc[nt] = __builtin_amdgcn_mfma_f32_16x16x32_bf16(a0, b0, acc[nt], 0, 0, 0);
      acc[nt] = __builtin_amdgcn_mfma_f32_16x16x32_bf16(a1, b1, acc[nt], 0, 0, 0);
    }
    __syncthreads();
  }

  if (mode == 0) {
    float* C = Cf + (size_t)bh * S_ * S_;
#pragma unroll
    for (int nt = 0; nt < 4; nt++) {
      int col = j0 + nt * 16 + m_lane;
#pragma unroll
      for (int r = 0; r < 4; r++) {
        int row = i0 + wave * 16 + quad * 4 + r;
        C[(size_t)row * S_ + col] = acc[nt][r];
      }
    }
  } else if (mode == 1) {
    float* C = Cf + (size_t)bh * S_ * S_;
#pragma unroll
    for (int nt = 0; nt < 4; nt++) {
      int t = j0 + nt * 16 + m_lane;
#pragma unroll
      for (int r = 0; r < 4; r++) {
        int row = i0 + wave * 16 + quad * 4 + r;
        int j = row + t - (S_ - 1);
        if (j >= 0) C[(size_t)row * S_ + j] += acc[nt][r];
      }
    }
  } else {
    u16* C = Cb + (size_t)b * S_ * D_ + h * DH_;
#pragma unroll
    for (int nt = 0; nt < 4; nt++) {
      int col = nt * 16 + m_lane;  // d
#pragma unroll
      for (int r = 0; r < 4; r++) {
        int row = i0 + wave * 16 + quad * 4 + r;
        C[(size_t)row * D_ + col] = f2bf(acc[nt][r]);
      }
    }
  }
}

// ---------------- softmax over causal row: single-pass float4, clipped load+store ----------------
__global__ __launch_bounds__(256) void softmax_k(const float* __restrict__ scores,
                                                 u16* __restrict__ aw,
                                                 const int* __restrict__ text) {
  const int i = blockIdx.x, bh = blockIdx.y, b = bh >> 4;
  const float* s = scores + ((size_t)bh * S_ + i) * S_;
  u16* o = aw + ((size_t)bh * S_ + i) * S_;
  const int tid = threadIdx.x, wave = tid >> 6, lane = tid & 63;
  const int n = i + 1;
  const int jmax = ((i >> 6) + 1) << 6;   // AV reads only j < jmax for this row's tile
  const int j0 = tid * 4;
  if (text[b * CTX_ + i] == PAD_) {       // fully-masked query row -> aw = 0
    if (j0 < jmax) ((ushort4*)o)[tid] = make_ushort4(0, 0, 0, 0);
    return;
  }
  const float scale = 0.125f;             // 1/sqrt(64)
  float4 sv = make_float4(0.f, 0.f, 0.f, 0.f);
  if (j0 < jmax) sv = ((const float4*)s)[tid];
  float e0 = (j0 + 0 < n) ? sv.x * scale : -3e38f;
  float e1 = (j0 + 1 < n) ? sv.y * scale : -3e38f;
  float e2 = (j0 + 2 < n) ? sv.z * scale : -3e38f;
  float e3 = (j0 + 3 < n) ? sv.w * scale : -3e38f;
  float mx = fmaxf(fmaxf(e0, e1), fmaxf(e2, e3));
  __shared__ float red[8];
#pragma unroll
  for (int off = 32; off > 0; off >>= 1) mx = fmaxf(mx, __shfl_xor(mx, off));
  if (lane == 0) red[wave] = mx;
  __syncthreads();
  mx = fmaxf(fmaxf(red[0], red[1]), fmaxf(red[2], red[3]));
  float p0 = __expf(e0 - mx);   // masked lanes: exp(-inf) = 0
  float p1 = __expf(e1 - mx);
  float p2 = __expf(e2 - mx);
  float p3 = __expf(e3 - mx);
  float sum = p0 + p1 + p2 + p3;
#pragma unroll
  for (int off = 32; off > 0; off >>= 1) sum += __shfl_xor(sum, off);
  if (lane == 0) red[4 + wave] = sum;
  __syncthreads();
  sum = red[4] + red[5] + red[6] + red[7];
  float inv = 1.0f / sum;
  if (j0 < jmax)
    ((ushort4*)o)[tid] = make_ushort4(f2bf(p0 * inv), f2bf(p1 * inv), f2bf(p2 * inv), f2bf(p3 * inv));
}

// ---------------- v transpose: (B*S, D) -> (B,H,DH,S) ----------------
__global__ __launch_bounds__(256) void v_transpose(const u16* __restrict__ v,
                                                   u16* __restrict__ vT) {
  int bh = blockIdx.y, b = bh >> 4, h = bh & 15;
  int j0 = blockIdx.x * 64;
  __shared__ u16 tile[64][65];
  for (int idx = threadIdx.x; idx < 4096; idx += 256) {
    int jj = idx >> 6, d = idx & 63;
    tile[jj][d] = v[(size_t)(b * S_ + j0 + jj) * D_ + h * DH_ + d];
  }
  __syncthreads();
  for (int idx = threadIdx.x; idx < 4096; idx += 256) {
    int d = idx >> 6, jj = idx & 63;
    vT[((size_t)bh * DH_ + d) * S_ + j0 + jj] = tile[jj][d];
  }
}

// =====================================================================
extern "C" void kernel_launch(void* const* d_in, const int* in_sizes, int n_in,
                              void* d_out, int out_size, void* d_ws, size_t ws_size,
                              hipStream_t stream) {
  (void)in_sizes; (void)n_in; (void)out_size;
  const int* text = (const int*)d_in[0];
  const float* emb = (const float*)d_in[1];
  const float* u_in = (const float*)d_in[2];
  const float* v_in = (const float*)d_in[3];
  const float* Wq = (const float*)d_in[4];
  const float* Wk = (const float*)d_in[5];
  const float* Wv = (const float*)d_in[6];
  const float* Wr = (const float*)d_in[7];
  const float* Wfc = (const float*)d_in[8];
  const float* bfc = (const float*)d_in[9];
  const float* ln1g = (const float*)d_in[10];
  const float* ln1b = (const float*)d_in[11];
  const float* ln2g = (const float*)d_in[12];
  const float* ln2b = (const float*)d_in[13];
  const float* W1 = (const float*)d_in[14];
  const float* b1 = (const float*)d_in[15];
  const float* W2 = (const float*)d_in[16];
  const float* b2 = (const float*)d_in[17];
  const float* lnfg = (const float*)d_in[18];
  const float* lnfb = (const float*)d_in[19];
  const float* Wlm = (const float*)d_in[20];
  const float* blm = (const float*)d_in[21];
  float* out = (float*)d_out;

  char* w = (char*)d_ws;
  size_t off = 0;
  auto alloc = [&](size_t bytes) -> void* {
    void* p = w + off;
    off += (bytes + 255) & ~(size_t)255;
    return p;
  };
  float* x      = (float*)alloc(2048ull * 1024 * 4);
  float* xnf    = (float*)alloc(2048ull * 1024 * 4);
  u16* xnb      = (u16*)alloc(2048ull * 1024 * 2);
  u16* relb     = (u16*)alloc(1024ull * 1024 * 2);
  u16* wqkvt    = (u16*)alloc(3072ull * 1024 * 2);   // [Wq^T | Wk^T | Wv^T]
  u16* wrt_all  = (u16*)alloc(4096ull * 1024 * 2);   // all 4 layers' Wr^T
  u16* wfct     = (u16*)alloc(1024ull * 1024 * 2);
  u16* w1t      = (u16*)alloc(4096ull * 1024 * 2);
  u16* w2t      = (u16*)alloc(4096ull * 1024 * 2);
  u16* wlmt     = (u16*)alloc(32000ull * 1024 * 2);
  u16* qu       = (u16*)alloc(2048ull * 1024 * 2);
  u16* qv       = (u16*)alloc(2048ull * 1024 * 2);
  u16* kk       = (u16*)alloc(2048ull * 1024 * 2);
  u16* vv       = (u16*)alloc(2048ull * 1024 * 2);
  u16* vT       = (u16*)alloc(2048ull * 1024 * 2);
  u16* rb_all   = (u16*)alloc(1024ull * 4096 * 2);   // rel @ Wr[l], all layers (ldc=4096)
  float* scores = (float*)alloc(32ull * 1024 * 1024 * 4);
  u16* aw       = (u16*)alloc(32ull * 1024 * 1024 * 2);
  u16* o_       = (u16*)alloc(2048ull * 1024 * 2);
  u16* f1       = (u16*)alloc(2048ull * 4096 * 2);
  if (off > ws_size) return;  // workspace too small; fail loudly via wrong output

  dim3 blk(256);
  embed_gather<<<2048, blk, 0, stream>>>(text, emb, x);
  rel_enc<<<1024, blk, 0, stream>>>(relb);
  wconv_t<<<dim3(1000, 32), blk, 0, stream>>>(Wlm, wlmt, 1024, 32000);
  // all 4 layers' Wr^T, then one batched R projection: rb_all = rel @ [Wr0|Wr1|Wr2|Wr3]
  wconv_t<<<dim3(32, 32, 4), blk, 0, stream>>>(Wr, wrt_all, 1024, 1024);
  gemm_bt<<<dim3(32, 8), blk, 0, stream>>>(relb, wrt_all, 1024, 4096, 1024,
                                           rb_all, nullptr, nullptr, nullptr,
                                           nullptr, nullptr, nullptr, 4096, EPI_BF16);

  for (int l = 0; l < 4; l++) {
    const size_t dd = 1048576;  // D*D
    wconv4_k<<<dim3(32, 32, 4), blk, 0, stream>>>(Wq + l * dd, Wk + l * dd, Wv + l * dd,
                                                  Wfc + l * dd, wqkvt, wfct);
    wconv_t<<<dim3(128, 32), blk, 0, stream>>>(W1 + l * 4ull * dd, w1t, 1024, 4096);
    wconv_t<<<dim3(32, 128), blk, 0, stream>>>(W2 + l * 4ull * dd, w2t, 4096, 1024);

    layernorm_k<<<2048, blk, 0, stream>>>(x, ln1g + l * 1024, ln1b + l * 1024, xnf, xnb);

    // fused Q/K/V projection: N=3072, 384 workgroups
    gemm_bt<<<dim3(24, 16), blk, 0, stream>>>(xnb, wqkvt, 2048, 3072, 1024,
                                              qu, qv, kk, vv, u_in, v_in, nullptr, 1024, EPI_QKV);
    v_transpose<<<dim3(16, 32), blk, 0, stream>>>(vv, vT);

    // fused AC + rel-shifted BD over the 136 causal tiles
    attn_score<<<dim3(136, 32), blk, 0, stream>>>(qu, qv, kk, rb_all + (size_t)l * 1024, scores);
    softmax_k<<<dim3(1024, 32), blk, 0, stream>>>(scores, aw, text);
    attn_gemm<<<dim3(16, 1, 32), blk, 0, stream>>>(aw, 1024, vT, 1024, nullptr, o_, 1024, 2);

    gemm_bt64<<<dim3(8, 32), blk, 0, stream>>>(o_, wfct, 2048, 1024, 1024,
                                               x, nullptr, nullptr, nullptr,
                                               bfc + l * 1024, nullptr, xnf, 1024, EPI_FC);
    layernorm_k<<<2048, blk, 0, stream>>>(x, ln2g + l * 1024, ln2b + l * 1024, nullptr, xnb);
    gemm_bt<<<dim3(32, 16), blk, 0, stream>>>(xnb, w1t, 2048, 4096, 1024,
                                              f1, nullptr, nullptr, nullptr,
                                              b1 + l * 4096, nullptr, nullptr, 4096, EPI_GELU_BF16);
    gemm_bt64<<<dim3(8, 32), blk, 0, stream>>>(f1, w2t, 2048, 1024, 4096,
                                               x, nullptr, nullptr, nullptr,
                                               b2 + l * 1024, nullptr, nullptr, 1024, EPI_GELU_RES);
  }

  layernorm_k<<<2048, blk, 0, stream>>>(x, lnfg, lnfb, nullptr, xnb);
  gemm_bt<<<dim3(250, 16), blk, 0, stream>>>(xnb, wlmt, 2048, 32000, 1024,
                                             out, nullptr, nullptr, nullptr,
                                             blm, nullptr, nullptr, 32000, EPI_BIAS_F32);
}

// Round 4
// 2311.479 us; speedup vs baseline: 1.0471x; 1.0162x over previous
//
#include <hip/hip_runtime.h>
#include <stdint.h>

#define S_ 1024
#define D_ 1024
#define H_ 16
#define DH_ 64
#define FF_ 4096
#define B_ 2
#define V_ 32000
#define CTX_ 1025
#define PAD_ 3

typedef unsigned short u16;
typedef __attribute__((ext_vector_type(8))) short bf16x8;
typedef __attribute__((ext_vector_type(4))) float f32x4;

enum { EPI_BF16 = 0, EPI_QKV = 1, EPI_FC = 2, EPI_GELU_BF16 = 3, EPI_GELU_RES = 4, EPI_BIAS_F32 = 5 };

__device__ __forceinline__ u16 f2bf(float f) {
  unsigned u = __float_as_uint(f);
  return (u16)((u + 0x7FFFu + ((u >> 16) & 1u)) >> 16);
}

__device__ __forceinline__ float bf2f(u16 v) {
  return __uint_as_float(((unsigned)v) << 16);
}

__device__ __forceinline__ float gelu_f(float x) {
  float t = tanhf(0.7978845608028654f * (x + 0.044715f * x * x * x));
  return 0.5f * x * (1.0f + t);
}

__device__ __forceinline__ void glds16(const void* g, void* l) {
  __builtin_amdgcn_global_load_lds(
      (const __attribute__((address_space(1))) unsigned int*)g,
      (__attribute__((address_space(3))) unsigned int*)l,
      16, 0, 0);
}

// ---------------- embedding gather ----------------
__global__ __launch_bounds__(256) void embed_gather(const int* __restrict__ text,
                                                    const float* __restrict__ emb,
                                                    float* __restrict__ x) {
  int row = blockIdx.x;             // 0..2047  (b*1024 + s)
  int b = row >> 10, s = row & 1023;
  int id = text[b * CTX_ + s];
  float4 v = ((const float4*)(emb + (size_t)id * D_))[threadIdx.x];
  ((float4*)(x + (size_t)row * D_))[threadIdx.x] = v;
}

// ---------------- relative positional encoding (bf16) ----------------
__global__ __launch_bounds__(256) void rel_enc(u16* __restrict__ rel) {
  int i = blockIdx.x;               // 0..1023
  float pos = (float)(S_ - 1 - i);
  for (int t = threadIdx.x; t < 512; t += 256) {
    float invf = exp2f(-(float)t * (13.287712379549449f / 512.0f)); // 10000^(-t/512)
    float ang = pos * invf;
    rel[(size_t)i * D_ + t] = f2bf(sinf(ang));
    rel[(size_t)i * D_ + 512 + t] = f2bf(cosf(ang));
  }
}

// ---------------- weight convert f32 (K,N) -> bf16 (N,K), z-batched ----------------
__global__ __launch_bounds__(256) void wconv_t(const float* __restrict__ src,
                                               u16* __restrict__ dst, int K, int N) {
  src += (size_t)blockIdx.z * K * N;
  dst += (size_t)blockIdx.z * K * N;
  __shared__ float tile[32][33];
  int n0 = blockIdx.x * 32, k0 = blockIdx.y * 32;
  for (int idx = threadIdx.x; idx < 1024; idx += 256) {
    int r = idx >> 5, c = idx & 31;                 // r: k, c: n
    tile[r][c] = src[(size_t)(k0 + r) * N + n0 + c];
  }
  __syncthreads();
  for (int idx = threadIdx.x; idx < 1024; idx += 256) {
    int r = idx >> 5, c = idx & 31;                 // r: n, c: k
    dst[(size_t)(n0 + r) * K + k0 + c] = f2bf(tile[c][r]);
  }
}

// ---------------- 4-way weight convert (Wq,Wk,Wv -> qkv segments; Wfc -> fc) ----------------
__global__ __launch_bounds__(256) void wconv4_k(const float* __restrict__ sq,
                                                const float* __restrict__ sk,
                                                const float* __restrict__ sv,
                                                const float* __restrict__ sf,
                                                u16* __restrict__ dqkv,
                                                u16* __restrict__ dfc) {
  const int z = blockIdx.z;
  const float* src = (z == 0) ? sq : (z == 1) ? sk : (z == 2) ? sv : sf;
  u16* dst = (z < 3) ? dqkv + (size_t)z * 1024 * 1024 : dfc;
  __shared__ float tile[32][33];
  int n0 = blockIdx.x * 32, k0 = blockIdx.y * 32;
  for (int idx = threadIdx.x; idx < 1024; idx += 256) {
    int r = idx >> 5, c = idx & 31;
    tile[r][c] = src[(size_t)(k0 + r) * 1024 + n0 + c];
  }
  __syncthreads();
  for (int idx = threadIdx.x; idx < 1024; idx += 256) {
    int r = idx >> 5, c = idx & 31;
    dst[(size_t)(n0 + r) * 1024 + k0 + c] = f2bf(tile[c][r]);
  }
}

// ---------------- layernorm (block per row) ----------------
__global__ __launch_bounds__(256) void layernorm_k(const float* __restrict__ x,
                                                   const float* __restrict__ g,
                                                   const float* __restrict__ bb,
                                                   float* __restrict__ outf,
                                                   u16* __restrict__ outb) {
  int row = blockIdx.x, tid = threadIdx.x;
  const float* xr = x + (size_t)row * D_;
  float4 v = ((const float4*)xr)[tid];
  float s = v.x + v.y + v.z + v.w;
  float s2 = v.x * v.x + v.y * v.y + v.z * v.z + v.w * v.w;
  __shared__ float red[8];
#pragma unroll
  for (int off = 32; off > 0; off >>= 1) { s += __shfl_xor(s, off); s2 += __shfl_xor(s2, off); }
  if ((tid & 63) == 0) { red[tid >> 6] = s; red[4 + (tid >> 6)] = s2; }
  __syncthreads();
  s = red[0] + red[1] + red[2] + red[3];
  s2 = red[4] + red[5] + red[6] + red[7];
  float mean = s * (1.0f / D_);
  float var = s2 * (1.0f / D_) - mean * mean;
  float rstd = rsqrtf(var + 1e-5f);
  float4 gv = ((const float4*)g)[tid];
  float4 bv = ((const float4*)bb)[tid];
  float y0 = (v.x - mean) * rstd * gv.x + bv.x;
  float y1 = (v.y - mean) * rstd * gv.y + bv.y;
  float y2 = (v.z - mean) * rstd * gv.z + bv.z;
  float y3 = (v.w - mean) * rstd * gv.w + bv.w;
  if (outf) ((float4*)(outf + (size_t)row * D_))[tid] = make_float4(y0, y1, y2, y3);
  ((ushort4*)(outb + (size_t)row * D_))[tid] = make_ushort4(f2bf(y0), f2bf(y1), f2bf(y2), f2bf(y3));
}

// ---------------- shared GEMM epilogue ----------------
__device__ __forceinline__ void epi_one(int mode, float v, int row, int col, int ldc,
                                        void* C0p, void* C1p, void* C2p, void* C3p,
                                        const float* bias0, const float* bias1,
                                        const float* res0) {
  if (mode == EPI_QKV) {
    // cols [0,1024): Q -> qu=q+u, qv=q+v ; [1024,2048): K ; [2048,3072): V
    int seg = col >> 10, c = col & 1023;
    size_t idx = (size_t)row * 1024 + c;
    if (seg == 0) {
      ((u16*)C0p)[idx] = f2bf(v + bias0[c]);
      ((u16*)C1p)[idx] = f2bf(v + bias1[c]);
    } else if (seg == 1) {
      ((u16*)C2p)[idx] = f2bf(v);
    } else {
      ((u16*)C3p)[idx] = f2bf(v);
    }
    return;
  }
  size_t idx = (size_t)row * ldc + col;
  float b0 = bias0 ? bias0[col] : 0.0f;
  if (mode == EPI_BF16) {
    ((u16*)C0p)[idx] = f2bf(v);
  } else if (mode == EPI_FC) {
    float* C0 = (float*)C0p;
    C0[idx] = C0[idx] + v + b0 + res0[idx];
  } else if (mode == EPI_GELU_BF16) {
    ((u16*)C0p)[idx] = f2bf(gelu_f(v + b0));
  } else if (mode == EPI_GELU_RES) {
    float* C0 = (float*)C0p;
    C0[idx] = C0[idx] + gelu_f(v + b0);
  } else { // EPI_BIAS_F32
    ((float*)C0p)[idx] = v + b0;
  }
}

// ---------------- main GEMM: C(M,N) = A(M,K) @ Bt(N,K)^T ----------------
// 128x128 tile, BK=64 (32 MFMA per barrier pair), 4 waves (2x2).
// LDS rows are 64 u16 (128B); 16-B chunks XOR-swizzled by slot^=(row&7) with
// pre-swizzled GLOBAL source + swizzled ds_read (rule: both-sides-or-neither).
// XCD column-clustering swizzle: B (big operand) fetched once chip-wide.
__global__ __launch_bounds__(256) void gemm_bt(const u16* __restrict__ A,
                                               const u16* __restrict__ Bt,
                                               int M, int N, int K,
                                               void* __restrict__ C0p, void* __restrict__ C1p,
                                               void* __restrict__ C2p, void* __restrict__ C3p,
                                               const float* __restrict__ bias0,
                                               const float* __restrict__ bias1,
                                               const float* __restrict__ res0,
                                               int ldc, int mode) {
  __shared__ u16 lA[128 * 64];
  __shared__ u16 lB[128 * 64];
  const int tid = threadIdx.x;
  const int wave = tid >> 6, lane = tid & 63;
  unsigned gx = gridDim.x, gy = gridDim.y;
  unsigned nwg = gx * gy;
  unsigned bx = blockIdx.x, by = blockIdx.y;
  if ((nwg & 7u) == 0u) {
    unsigned lin = by * gx + bx;
    unsigned v = (lin & 7u) * (nwg >> 3) + (lin >> 3);
    bx = v / gy;            // column tile (consecutive v share a column)
    by = v - bx * gy;       // row tile
  }
  const int i0 = by * 128, j0 = bx * 128;
  const int wm = wave & 1, wn = wave >> 1;
  const int m_lane = lane & 15, quad = lane >> 4;

  f32x4 acc[4][4] = {};

  const u16* Ab = A + (size_t)i0 * K;
  const u16* Bb = Bt + (size_t)j0 * K;
  const int sr = lane >> 3;                       // 0..7 row within 8-row stage group
  const int sc = ((lane & 7) ^ sr) * 8;           // pre-swizzled source u16 col

  for (int k0 = 0; k0 < K; k0 += 64) {
#pragma unroll
    for (int c = 0; c < 4; c++) {
      int row = wave * 32 + c * 8 + sr;           // row&7 == sr
      glds16(Ab + (size_t)row * K + k0 + sc, lA + (size_t)(wave * 32 + c * 8) * 64);
      glds16(Bb + (size_t)row * K + k0 + sc, lB + (size_t)(wave * 32 + c * 8) * 64);
    }
    __syncthreads();
    bf16x8 af[4], bfr[4];
    // half-phase 0: k = 0..31 of this BK (logical slots quad)
#pragma unroll
    for (int t = 0; t < 4; t++) {
      int ra = wm * 64 + t * 16 + m_lane;
      int rb_ = wn * 64 + t * 16 + m_lane;
      af[t]  = *(const bf16x8*)(lA + ra * 64 + ((quad ^ (ra & 7)) * 8));
      bfr[t] = *(const bf16x8*)(lB + rb_ * 64 + ((quad ^ (rb_ & 7)) * 8));
    }
#pragma unroll
    for (int mt = 0; mt < 4; mt++)
#pragma unroll
      for (int nt = 0; nt < 4; nt++)
        acc[mt][nt] = __builtin_amdgcn_mfma_f32_16x16x32_bf16(af[mt], bfr[nt], acc[mt][nt], 0, 0, 0);
    // half-phase 1: k = 32..63 (logical slots 4+quad)
#pragma unroll
    for (int t = 0; t < 4; t++) {
      int ra = wm * 64 + t * 16 + m_lane;
      int rb_ = wn * 64 + t * 16 + m_lane;
      af[t]  = *(const bf16x8*)(lA + ra * 64 + (((4 + quad) ^ (ra & 7)) * 8));
      bfr[t] = *(const bf16x8*)(lB + rb_ * 64 + (((4 + quad) ^ (rb_ & 7)) * 8));
    }
#pragma unroll
    for (int mt = 0; mt < 4; mt++)
#pragma unroll
      for (int nt = 0; nt < 4; nt++)
        acc[mt][nt] = __builtin_amdgcn_mfma_f32_16x16x32_bf16(af[mt], bfr[nt], acc[mt][nt], 0, 0, 0);
    __syncthreads();
  }

#pragma unroll
  for (int mt = 0; mt < 4; mt++) {
#pragma unroll
    for (int nt = 0; nt < 4; nt++) {
      int col = j0 + wn * 64 + nt * 16 + m_lane;
#pragma unroll
      for (int r = 0; r < 4; r++) {
        int row = i0 + wm * 64 + mt * 16 + quad * 4 + r;
        epi_one(mode, acc[mt][nt][r], row, col, ldc, C0p, C1p, C2p, C3p, bias0, bias1, res0);
      }
    }
  }
}

// ---------------- 64x128-tile GEMM variant (for N=1024 outputs) ----------------
// BK=64, same swizzle scheme; ROW-clustering XCD swizzle (A is the big operand for ff2).
__global__ __launch_bounds__(256) void gemm_bt64(const u16* __restrict__ A,
                                                 const u16* __restrict__ Bt,
                                                 int M, int N, int K,
                                                 void* __restrict__ C0p, void* __restrict__ C1p,
                                                 void* __restrict__ C2p, void* __restrict__ C3p,
                                                 const float* __restrict__ bias0,
                                                 const float* __restrict__ bias1,
                                                 const float* __restrict__ res0,
                                                 int ldc, int mode) {
  __shared__ u16 lA[64 * 64];
  __shared__ u16 lB[128 * 64];
  const int tid = threadIdx.x;
  const int wave = tid >> 6, lane = tid & 63;
  unsigned gx = gridDim.x, gy = gridDim.y;
  unsigned nwg = gx * gy;
  unsigned bx = blockIdx.x, by = blockIdx.y;
  if ((nwg & 7u) == 0u) {
    unsigned lin = by * gx + bx;
    unsigned v = (lin & 7u) * (nwg >> 3) + (lin >> 3);
    by = v / gx;            // row tile (consecutive v share a row)
    bx = v - by * gx;       // column tile
  }
  const int i0 = by * 64, j0 = bx * 128;
  const int m_lane = lane & 15, quad = lane >> 4;

  f32x4 acc[4][2] = {};

  const u16* Ab = A + (size_t)i0 * K;
  const u16* Bb = Bt + (size_t)j0 * K;
  const int sr = lane >> 3;
  const int sc = ((lane & 7) ^ sr) * 8;

  for (int k0 = 0; k0 < K; k0 += 64) {
#pragma unroll
    for (int c = 0; c < 2; c++) {
      int row = wave * 16 + c * 8 + sr;           // A rows: 64 total
      glds16(Ab + (size_t)row * K + k0 + sc, lA + (size_t)(wave * 16 + c * 8) * 64);
    }
#pragma unroll
    for (int c = 0; c < 4; c++) {
      int row = wave * 32 + c * 8 + sr;           // B rows: 128 total
      glds16(Bb + (size_t)row * K + k0 + sc, lB + (size_t)(wave * 32 + c * 8) * 64);
    }
    __syncthreads();
    bf16x8 af[4], bfr[2];
#pragma unroll
    for (int t = 0; t < 4; t++) {
      int ra = t * 16 + m_lane;
      af[t] = *(const bf16x8*)(lA + ra * 64 + ((quad ^ (ra & 7)) * 8));
    }
#pragma unroll
    for (int t = 0; t < 2; t++) {
      int rb_ = wave * 32 + t * 16 + m_lane;
      bfr[t] = *(const bf16x8*)(lB + rb_ * 64 + ((quad ^ (rb_ & 7)) * 8));
    }
#pragma unroll
    for (int mt = 0; mt < 4; mt++)
#pragma unroll
      for (int nt = 0; nt < 2; nt++)
        acc[mt][nt] = __builtin_amdgcn_mfma_f32_16x16x32_bf16(af[mt], bfr[nt], acc[mt][nt], 0, 0, 0);
#pragma unroll
    for (int t = 0; t < 4; t++) {
      int ra = t * 16 + m_lane;
      af[t] = *(const bf16x8*)(lA + ra * 64 + (((4 + quad) ^ (ra & 7)) * 8));
    }
#pragma unroll
    for (int t = 0; t < 2; t++) {
      int rb_ = wave * 32 + t * 16 + m_lane;
      bfr[t] = *(const bf16x8*)(lB + rb_ * 64 + (((4 + quad) ^ (rb_ & 7)) * 8));
    }
#pragma unroll
    for (int mt = 0; mt < 4; mt++)
#pragma unroll
      for (int nt = 0; nt < 2; nt++)
        acc[mt][nt] = __builtin_amdgcn_mfma_f32_16x16x32_bf16(af[mt], bfr[nt], acc[mt][nt], 0, 0, 0);
    __syncthreads();
  }

#pragma unroll
  for (int mt = 0; mt < 4; mt++) {
#pragma unroll
    for (int nt = 0; nt < 2; nt++) {
      int col = j0 + wave * 32 + nt * 16 + m_lane;
#pragma unroll
      for (int r = 0; r < 4; r++) {
        int row = i0 + mt * 16 + quad * 4 + r;
        epi_one(mode, acc[mt][nt][r], row, col, ldc, C0p, C1p, C2p, C3p, bias0, bias1, res0);
      }
    }
  }
}

// ---------------- fused attention score: AC + rel-shifted BD, one pass ----------------
// grid (136, 32): blockIdx.x = causal tile index c -> (ti,tj) with tj<=ti,
// blockIdx.y = bh. Writes scores[i][j] = qu_i.k_j + qv_i.r_{j-i+1023} (unscaled).
__global__ __launch_bounds__(256) void attn_score(const u16* __restrict__ qu,
                                                  const u16* __restrict__ qv,
                                                  const u16* __restrict__ kk,
                                                  const u16* __restrict__ rb, // + l*1024, row stride 4096
                                                  float* __restrict__ scores) {
  __shared__ u16 sBD[64][132];   // +4 pad: quad rows shift banks by 8 -> conflict-free
  const int cIdx = blockIdx.x, bh = blockIdx.y;
  int ti = (int)((sqrtf(8.0f * (float)cIdx + 1.0f) - 1.0f) * 0.5f);
  while ((ti + 1) * (ti + 2) / 2 <= cIdx) ti++;
  while (ti * (ti + 1) / 2 > cIdx) ti--;
  const int tj = cIdx - ti * (ti + 1) / 2;
  const int b = bh >> 4, h = bh & 15;
  const int tid = threadIdx.x, wave = tid >> 6, lane = tid & 63;
  const int m_lane = lane & 15, quad = lane >> 4;
  const int i0 = ti * 64, j0 = tj * 64;
  const int T0 = 15 - (ti - tj);
  const bool hasT1 = (T0 < 15);

  // A fragments direct from global (rows i0+wave*16+m_lane, cols h*64+quad*8)
  const u16* Qu = qu + ((size_t)(b * S_ + i0 + wave * 16 + m_lane)) * D_ + h * DH_ + quad * 8;
  const u16* Qv = qv + ((size_t)(b * S_ + i0 + wave * 16 + m_lane)) * D_ + h * DH_ + quad * 8;
  bf16x8 a0 = *(const bf16x8*)(Qu);
  bf16x8 a1 = *(const bf16x8*)(Qu + 32);
  bf16x8 c0 = *(const bf16x8*)(Qv);
  bf16x8 c1 = *(const bf16x8*)(Qv + 32);

  const u16* Kb = kk + ((size_t)(b * S_ + j0)) * D_ + h * DH_;
  const u16* R0 = rb + ((size_t)(T0 * 64)) * 4096 + h * DH_;
  const u16* R1 = R0 + (size_t)64 * 4096;

  f32x4 ac_[4] = {}, bd0_[4] = {}, bd1_[4] = {};
#pragma unroll
  for (int nt = 0; nt < 4; nt++) {
    const u16* kr = Kb + (size_t)(nt * 16 + m_lane) * D_ + quad * 8;
    bf16x8 kb0 = *(const bf16x8*)(kr);
    bf16x8 kb1 = *(const bf16x8*)(kr + 32);
    ac_[nt] = __builtin_amdgcn_mfma_f32_16x16x32_bf16(a0, kb0, ac_[nt], 0, 0, 0);
    ac_[nt] = __builtin_amdgcn_mfma_f32_16x16x32_bf16(a1, kb1, ac_[nt], 0, 0, 0);
    const u16* rr = R0 + (size_t)(nt * 16 + m_lane) * 4096 + quad * 8;
    bf16x8 rb0 = *(const bf16x8*)(rr);
    bf16x8 rb1 = *(const bf16x8*)(rr + 32);
    bd0_[nt] = __builtin_amdgcn_mfma_f32_16x16x32_bf16(c0, rb0, bd0_[nt], 0, 0, 0);
    bd0_[nt] = __builtin_amdgcn_mfma_f32_16x16x32_bf16(c1, rb1, bd0_[nt], 0, 0, 0);
    if (hasT1) {
      const u16* r2 = R1 + (size_t)(nt * 16 + m_lane) * 4096 + quad * 8;
      bf16x8 rc0 = *(const bf16x8*)(r2);
      bf16x8 rc1 = *(const bf16x8*)(r2 + 32);
      bd1_[nt] = __builtin_amdgcn_mfma_f32_16x16x32_bf16(c0, rc0, bd1_[nt], 0, 0, 0);
      bd1_[nt] = __builtin_amdgcn_mfma_f32_16x16x32_bf16(c1, rc1, bd1_[nt], 0, 0, 0);
    }
  }

  // BD (i,t) tiles -> LDS (bf16). Each wave writes/reads only its own 16 rows.
#pragma unroll
  for (int nt = 0; nt < 4; nt++) {
    int col = nt * 16 + m_lane;
#pragma unroll
    for (int r = 0; r < 4; r++) {
      int row = wave * 16 + quad * 4 + r;
      sBD[row][col] = f2bf(bd0_[nt][r]);
      sBD[row][64 + col] = hasT1 ? f2bf(bd1_[nt][r]) : (u16)0;
    }
  }
  __syncthreads();

  float* C = scores + (size_t)bh * S_ * S_ + (size_t)i0 * S_ + j0;
#pragma unroll
  for (int nt = 0; nt < 4; nt++) {
    int jl = nt * 16 + m_lane;
#pragma unroll
    for (int r = 0; r < 4; r++) {
      int il = wave * 16 + quad * 4 + r;
      int tloc = jl - il + 63;          // in [0,126]; >63 only in masked or hasT1 region
      C[(size_t)il * S_ + jl] = ac_[nt][r] + bf2f(sBD[il][tloc]);
    }
  }
}

// ---------------- batched attention GEMM (mode 2 = AV used) ----------------
// LDS chunk-swizzled like gemm_bt (rows are 128B).
__global__ __launch_bounds__(256) void attn_gemm(const u16* __restrict__ A, int lda,
                                                 const u16* __restrict__ Bt, int ldb,
                                                 float* __restrict__ Cf, u16* __restrict__ Cb,
                                                 int K, int mode) {
  const int ti = blockIdx.x, tj = blockIdx.y, bh = blockIdx.z;
  if (mode == 0 && tj > ti) return;
  if (mode == 1 && ti + tj < 15) return;
  const int b = bh >> 4, h = bh & 15;
  __shared__ u16 lA[64 * 64];
  __shared__ u16 lB[64 * 64];
  const int tid = threadIdx.x, wave = tid >> 6, lane = tid & 63;
  const int m_lane = lane & 15, quad = lane >> 4;
  const int i0 = ti * 64, j0 = tj * 64;

  size_t aoff, boff;
  if (mode == 0)      { aoff = (size_t)b * S_ * D_ + h * DH_; boff = (size_t)b * S_ * D_ + h * DH_; }
  else if (mode == 1) { aoff = (size_t)b * S_ * D_ + h * DH_; boff = (size_t)h * DH_; }
  else                { aoff = (size_t)bh * S_ * S_;          boff = (size_t)bh * DH_ * S_; }
  const u16* Ap = A + aoff + (size_t)i0 * lda;
  const u16* Bp = Bt + boff + (mode == 2 ? (size_t)0 : (size_t)j0 * ldb);

  f32x4 acc[4] = {};
  // stage: rows wave*16 + c*8 + (lane>>3); pre-swizzled source slot
  const int sr = lane >> 3;                  // row&7 within stage group
  const int sc = ((lane & 7) ^ sr) * 8;      // swizzled source u16 col

  const int Kend = (mode == 2) ? (ti + 1) * 64 : K;   // causal clip for AV
  for (int k0 = 0; k0 < Kend; k0 += 64) {
#pragma unroll
    for (int c = 0; c < 2; c++) {
      int row = wave * 16 + c * 8 + sr;
      glds16(Ap + (size_t)row * lda + k0 + sc, lA + (size_t)(wave * 16 + c * 8) * 64);
      glds16(Bp + (size_t)row * ldb + k0 + sc, lB + (size_t)(wave * 16 + c * 8) * 64);
    }
    __syncthreads();
    int ra = wave * 16 + m_lane;
    bf16x8 a0 = *(const bf16x8*)(lA + ra * 64 + ((quad ^ (ra & 7)) * 8));
    bf16x8 a1 = *(const bf16x8*)(lA + ra * 64 + (((4 + quad) ^ (ra & 7)) * 8));
#pragma unroll
    for (int nt = 0; nt < 4; nt++) {
      int rb_ = nt * 16 + m_lane;
      bf16x8 b0 = *(const bf16x8*)(lB + rb_ * 64 + ((quad ^ (rb_ & 7)) * 8));
      bf16x8 b1 = *(const bf16x8*)(lB + rb_ * 64 + (((4 + quad) ^ (rb_ & 7)) * 8));
      acc[nt] = __builtin_amdgcn_mfma_f32_16x16x32_bf16(a0, b0, acc[nt], 0, 0, 0);
      acc[nt] = __builtin_amdgcn_mfma_f32_16x16x32_bf16(a1, b1, acc[nt], 0, 0, 0);
    }
    __syncthreads();
  }

  if (mode == 0) {
    float* C = Cf + (size_t)bh * S_ * S_;
#pragma unroll
    for (int nt = 0; nt < 4; nt++) {
      int col = j0 + nt * 16 + m_lane;
#pragma unroll
      for (int r = 0; r < 4; r++) {
        int row = i0 + wave * 16 + quad * 4 + r;
        C[(size_t)row * S_ + col] = acc[nt][r];
      }
    }
  } else if (mode == 1) {
    float* C = Cf + (size_t)bh * S_ * S_;
#pragma unroll
    for (int nt = 0; nt < 4; nt++) {
      int t = j0 + nt * 16 + m_lane;
#pragma unroll
      for (int r = 0; r < 4; r++) {
        int row = i0 + wave * 16 + quad * 4 + r;
        int j = row + t - (S_ - 1);
        if (j >= 0) C[(size_t)row * S_ + j] += acc[nt][r];
      }
    }
  } else {
    u16* C = Cb + (size_t)b * S_ * D_ + h * DH_;
#pragma unroll
    for (int nt = 0; nt < 4; nt++) {
      int col = nt * 16 + m_lane;  // d
#pragma unroll
      for (int r = 0; r < 4; r++) {
        int row = i0 + wave * 16 + quad * 4 + r;
        C[(size_t)row * D_ + col] = f2bf(acc[nt][r]);
      }
    }
  }
}

// ---------------- softmax over causal row: single-pass float4, clipped load+store ----------------
__global__ __launch_bounds__(256) void softmax_k(const float* __restrict__ scores,
                                                 u16* __restrict__ aw,
                                                 const int* __restrict__ text) {
  const int i = blockIdx.x, bh = blockIdx.y, b = bh >> 4;
  const float* s = scores + ((size_t)bh * S_ + i) * S_;
  u16* o = aw + ((size_t)bh * S_ + i) * S_;
  const int tid = threadIdx.x, wave = tid >> 6, lane = tid & 63;
  const int n = i + 1;
  const int jmax = ((i >> 6) + 1) << 6;   // AV reads only j < jmax for this row's tile
  const int j0 = tid * 4;
  if (text[b * CTX_ + i] == PAD_) {       // fully-masked query row -> aw = 0
    if (j0 < jmax) ((ushort4*)o)[tid] = make_ushort4(0, 0, 0, 0);
    return;
  }
  const float scale = 0.125f;             // 1/sqrt(64)
  float4 sv = make_float4(0.f, 0.f, 0.f, 0.f);
  if (j0 < jmax) sv = ((const float4*)s)[tid];
  float e0 = (j0 + 0 < n) ? sv.x * scale : -3e38f;
  float e1 = (j0 + 1 < n) ? sv.y * scale : -3e38f;
  float e2 = (j0 + 2 < n) ? sv.z * scale : -3e38f;
  float e3 = (j0 + 3 < n) ? sv.w * scale : -3e38f;
  float mx = fmaxf(fmaxf(e0, e1), fmaxf(e2, e3));
  __shared__ float red[8];
#pragma unroll
  for (int off = 32; off > 0; off >>= 1) mx = fmaxf(mx, __shfl_xor(mx, off));
  if (lane == 0) red[wave] = mx;
  __syncthreads();
  mx = fmaxf(fmaxf(red[0], red[1]), fmaxf(red[2], red[3]));
  float p0 = __expf(e0 - mx);   // masked lanes: exp(-inf) = 0
  float p1 = __expf(e1 - mx);
  float p2 = __expf(e2 - mx);
  float p3 = __expf(e3 - mx);
  float sum = p0 + p1 + p2 + p3;
#pragma unroll
  for (int off = 32; off > 0; off >>= 1) sum += __shfl_xor(sum, off);
  if (lane == 0) red[4 + wave] = sum;
  __syncthreads();
  sum = red[4] + red[5] + red[6] + red[7];
  float inv = 1.0f / sum;
  if (j0 < jmax)
    ((ushort4*)o)[tid] = make_ushort4(f2bf(p0 * inv), f2bf(p1 * inv), f2bf(p2 * inv), f2bf(p3 * inv));
}

// ---------------- v transpose: (B*S, D) -> (B,H,DH,S) ----------------
__global__ __launch_bounds__(256) void v_transpose(const u16* __restrict__ v,
                                                   u16* __restrict__ vT) {
  int bh = blockIdx.y, b = bh >> 4, h = bh & 15;
  int j0 = blockIdx.x * 64;
  __shared__ u16 tile[64][65];
  for (int idx = threadIdx.x; idx < 4096; idx += 256) {
    int jj = idx >> 6, d = idx & 63;
    tile[jj][d] = v[(size_t)(b * S_ + j0 + jj) * D_ + h * DH_ + d];
  }
  __syncthreads();
  for (int idx = threadIdx.x; idx < 4096; idx += 256) {
    int d = idx >> 6, jj = idx & 63;
    vT[((size_t)bh * DH_ + d) * S_ + j0 + jj] = tile[jj][d];
  }
}

// =====================================================================
extern "C" void kernel_launch(void* const* d_in, const int* in_sizes, int n_in,
                              void* d_out, int out_size, void* d_ws, size_t ws_size,
                              hipStream_t stream) {
  (void)in_sizes; (void)n_in; (void)out_size;
  const int* text = (const int*)d_in[0];
  const float* emb = (const float*)d_in[1];
  const float* u_in = (const float*)d_in[2];
  const float* v_in = (const float*)d_in[3];
  const float* Wq = (const float*)d_in[4];
  const float* Wk = (const float*)d_in[5];
  const float* Wv = (const float*)d_in[6];
  const float* Wr = (const float*)d_in[7];
  const float* Wfc = (const float*)d_in[8];
  const float* bfc = (const float*)d_in[9];
  const float* ln1g = (const float*)d_in[10];
  const float* ln1b = (const float*)d_in[11];
  const float* ln2g = (const float*)d_in[12];
  const float* ln2b = (const float*)d_in[13];
  const float* W1 = (const float*)d_in[14];
  const float* b1 = (const float*)d_in[15];
  const float* W2 = (const float*)d_in[16];
  const float* b2 = (const float*)d_in[17];
  const float* lnfg = (const float*)d_in[18];
  const float* lnfb = (const float*)d_in[19];
  const float* Wlm = (const float*)d_in[20];
  const float* blm = (const float*)d_in[21];
  float* out = (float*)d_out;

  char* w = (char*)d_ws;
  size_t off = 0;
  auto alloc = [&](size_t bytes) -> void* {
    void* p = w + off;
    off += (bytes + 255) & ~(size_t)255;
    return p;
  };
  float* x      = (float*)alloc(2048ull * 1024 * 4);
  float* xnf    = (float*)alloc(2048ull * 1024 * 4);
  u16* xnb      = (u16*)alloc(2048ull * 1024 * 2);
  u16* relb     = (u16*)alloc(1024ull * 1024 * 2);
  u16* wqkvt    = (u16*)alloc(3072ull * 1024 * 2);   // [Wq^T | Wk^T | Wv^T]
  u16* wrt_all  = (u16*)alloc(4096ull * 1024 * 2);   // all 4 layers' Wr^T
  u16* wfct     = (u16*)alloc(1024ull * 1024 * 2);
  u16* w1t      = (u16*)alloc(4096ull * 1024 * 2);
  u16* w2t      = (u16*)alloc(4096ull * 1024 * 2);
  u16* wlmt     = (u16*)alloc(32000ull * 1024 * 2);
  u16* qu       = (u16*)alloc(2048ull * 1024 * 2);
  u16* qv       = (u16*)alloc(2048ull * 1024 * 2);
  u16* kk       = (u16*)alloc(2048ull * 1024 * 2);
  u16* vv       = (u16*)alloc(2048ull * 1024 * 2);
  u16* vT       = (u16*)alloc(2048ull * 1024 * 2);
  u16* rb_all   = (u16*)alloc(1024ull * 4096 * 2);   // rel @ Wr[l], all layers (ldc=4096)
  float* scores = (float*)alloc(32ull * 1024 * 1024 * 4);
  u16* aw       = (u16*)alloc(32ull * 1024 * 1024 * 2);
  u16* o_       = (u16*)alloc(2048ull * 1024 * 2);
  u16* f1       = (u16*)alloc(2048ull * 4096 * 2);
  if (off > ws_size) return;  // workspace too small; fail loudly via wrong output

  dim3 blk(256);
  embed_gather<<<2048, blk, 0, stream>>>(text, emb, x);
  rel_enc<<<1024, blk, 0, stream>>>(relb);
  wconv_t<<<dim3(1000, 32), blk, 0, stream>>>(Wlm, wlmt, 1024, 32000);
  // all 4 layers' Wr^T, then one batched R projection: rb_all = rel @ [Wr0|Wr1|Wr2|Wr3]
  wconv_t<<<dim3(32, 32, 4), blk, 0, stream>>>(Wr, wrt_all, 1024, 1024);
  gemm_bt<<<dim3(32, 8), blk, 0, stream>>>(relb, wrt_all, 1024, 4096, 1024,
                                           rb_all, nullptr, nullptr, nullptr,
                                           nullptr, nullptr, nullptr, 4096, EPI_BF16);

  for (int l = 0; l < 4; l++) {
    const size_t dd = 1048576;  // D*D
    wconv4_k<<<dim3(32, 32, 4), blk, 0, stream>>>(Wq + l * dd, Wk + l * dd, Wv + l * dd,
                                                  Wfc + l * dd, wqkvt, wfct);
    wconv_t<<<dim3(128, 32), blk, 0, stream>>>(W1 + l * 4ull * dd, w1t, 1024, 4096);
    wconv_t<<<dim3(32, 128), blk, 0, stream>>>(W2 + l * 4ull * dd, w2t, 4096, 1024);

    layernorm_k<<<2048, blk, 0, stream>>>(x, ln1g + l * 1024, ln1b + l * 1024, xnf, xnb);

    // fused Q/K/V projection: N=3072, 384 workgroups
    gemm_bt<<<dim3(24, 16), blk, 0, stream>>>(xnb, wqkvt, 2048, 3072, 1024,
                                              qu, qv, kk, vv, u_in, v_in, nullptr, 1024, EPI_QKV);
    v_transpose<<<dim3(16, 32), blk, 0, stream>>>(vv, vT);

    // fused AC + rel-shifted BD over the 136 causal tiles
    attn_score<<<dim3(136, 32), blk, 0, stream>>>(qu, qv, kk, rb_all + (size_t)l * 1024, scores);
    softmax_k<<<dim3(1024, 32), blk, 0, stream>>>(scores, aw, text);
    attn_gemm<<<dim3(16, 1, 32), blk, 0, stream>>>(aw, 1024, vT, 1024, nullptr, o_, 1024, 2);

    gemm_bt64<<<dim3(8, 32), blk, 0, stream>>>(o_, wfct, 2048, 1024, 1024,
                                               x, nullptr, nullptr, nullptr,
                                               bfc + l * 1024, nullptr, xnf, 1024, EPI_FC);
    layernorm_k<<<2048, blk, 0, stream>>>(x, ln2g + l * 1024, ln2b + l * 1024, nullptr, xnb);
    gemm_bt<<<dim3(32, 16), blk, 0, stream>>>(xnb, w1t, 2048, 4096, 1024,
                                              f1, nullptr, nullptr, nullptr,
                                              b1 + l * 4096, nullptr, nullptr, 4096, EPI_GELU_BF16);
    gemm_bt64<<<dim3(8, 32), blk, 0, stream>>>(f1, w2t, 2048, 1024, 4096,
                                               x, nullptr, nullptr, nullptr,
                                               b2 + l * 1024, nullptr, nullptr, 1024, EPI_GELU_RES);
  }

  layernorm_k<<<2048, blk, 0, stream>>>(x, lnfg, lnfb, nullptr, xnb);
  gemm_bt<<<dim3(250, 16), blk, 0, stream>>>(xnb, wlmt, 2048, 32000, 1024,
                                             out, nullptr, nullptr, nullptr,
                                             blm, nullptr, nullptr, 32000, EPI_BIAS_F32);
}